// Round 2
// baseline (6347.043 us; speedup 1.0000x reference)
//
#include <hip/hip_runtime.h>
#include <math.h>

#define B_ 4
#define C_ 128
#define HW_ 65536
#define H__ 256
#define KF_ 129
#define PLANEF_ 33024

__device__ __forceinline__ float geluf(float x) {
    return 0.5f * x * (1.f + erff(x * 0.70710678118654752f));
}

// ---------------------------------------------------------------- prep
__global__ __launch_bounds__(256) void transpose_kernel(const float* __restrict__ src,
                                                        float* __restrict__ dst, int O, int Cc)
{
    int i = blockIdx.x * 256 + threadIdx.x;
    if (i < O * Cc) {
        int o = i / Cc, c = i % Cc;
        dst[(size_t)c * O + o] = src[i];
    }
}

__global__ void ksum_kernel(const float* __restrict__ dw, float* __restrict__ ks)
{
    int c = threadIdx.x;
    if (c < C_) {
        float s = 0.f;
        for (int k = 0; k < 9; ++k) s += dw[c * 9 + k];
        ks[c] = s;
    }
}

// ---------------------------------------------------------------- per-pixel LayerNorm stats
// per-batch (grid 256): p < 65536 -> b=0.  full (grid 1024): b = p>>16.
__global__ __launch_bounds__(256) void ln_stats_kernel(const float* __restrict__ Xa,
                                                       const float* __restrict__ Xb,
                                                       float* __restrict__ mu, float* __restrict__ inv)
{
    int p = blockIdx.x * 256 + threadIdx.x;
    int b = p >> 16, pp = p & 65535;
    const float* a = Xa + (size_t)b * C_ * HW_ + pp;
    float s = 0.f, s2 = 0.f;
    for (int c = 0; c < C_; ++c) { float v = a[(size_t)c * HW_]; s += v; s2 += v * v; }
    float n = (float)C_;
    if (Xb) {
        const float* bb = Xb + (size_t)b * C_ * HW_ + pp;
        for (int c = 0; c < C_; ++c) { float v = bb[(size_t)c * HW_]; s += v; s2 += v * v; }
        n = 2.f * C_;
    }
    float m = s / n;
    float var = s2 / n - m * m;
    mu[p] = m;
    inv[p] = rsqrtf(var + 1e-5f);
}

// ---------------------------------------------------------------- register-tiled conv1x1
// OP: 0 float, 1 |float2|, 2 angle(float2).  PRO: 1 = leaky(0.1) on staged value.
// LNF: LN-normalize staged value. flags&1: +1e-8 after bias. res: added (use res=Y to accumulate).
template<int CIN, int COUT, int KC, int TP, int OP, int PRO, bool LNF>
__global__ __launch_bounds__(256) void convk(
    const void* __restrict__ X0v, const void* __restrict__ X1v, int csplit,
    const float* __restrict__ Wt, const float* __restrict__ bias,
    const float* __restrict__ res, float* __restrict__ Y, int plane, int flags,
    const float* __restrict__ lnmu, const float* __restrict__ lninv,
    const float* __restrict__ lnw, const float* __restrict__ lnb)
{
    constexpr int PG = TP / 4;
    constexpr int OG = 256 / PG;
    constexpr int OPT = COUT / OG;
    static_assert(OPT % 4 == 0, "OPT must be multiple of 4");

    __shared__ __align__(16) float xs[KC][TP];
    __shared__ __align__(16) float ws[KC][COUT];

    const int b = blockIdx.y;
    const int p0 = blockIdx.x * TP;
    const int t = threadIdx.x;
    const int pg = t % PG;
    const int og = t / PG;

    float acc[4][OPT];
#pragma unroll
    for (int px = 0; px < 4; ++px)
#pragma unroll
        for (int j = 0; j < OPT; ++j) acc[px][j] = 0.f;

    for (int c0 = 0; c0 < CIN; c0 += KC) {
        for (int e = t; e < KC * TP; e += 256) {
            int c = e / TP, p = e % TP;
            int cg = c0 + c;
            bool inA = (cg < csplit);
            int ch = inA ? cg : (cg - csplit);
            int nch = inA ? csplit : (CIN - csplit);
            const void* Xv = inA ? X0v : X1v;
            size_t idx = ((size_t)b * nch + ch) * (size_t)plane + (size_t)(p0 + p);
            float v;
            if constexpr (OP == 0) {
                v = ((const float*)Xv)[idx];
            } else if constexpr (OP == 1) {
                float2 z = ((const float2*)Xv)[idx];
                v = sqrtf(z.x * z.x + z.y * z.y);
            } else {
                float2 z = ((const float2*)Xv)[idx];
                v = atan2f(z.y, z.x);
            }
            if constexpr (PRO == 1) v = (v > 0.f) ? v : 0.1f * v;
            if constexpr (LNF) {
                size_t pix = (size_t)b * (size_t)plane + (size_t)(p0 + p);
                v = (v - lnmu[pix]) * lninv[pix] * lnw[cg] + lnb[cg];
            }
            xs[c][p] = v;
        }
        for (int e = t; e < KC * COUT; e += 256) {
            int c = e / COUT, o = e % COUT;
            ws[c][o] = Wt[(size_t)(c0 + c) * COUT + o];
        }
        __syncthreads();
#pragma unroll 8
        for (int c = 0; c < KC; ++c) {
            float4 xv = *(const float4*)&xs[c][pg * 4];
            float xa[4] = {xv.x, xv.y, xv.z, xv.w};
#pragma unroll
            for (int j = 0; j < OPT; j += 4) {
                float4 wv = *(const float4*)&ws[c][og * OPT + j];
                float wa[4] = {wv.x, wv.y, wv.z, wv.w};
#pragma unroll
                for (int px = 0; px < 4; ++px)
#pragma unroll
                    for (int k = 0; k < 4; ++k)
                        acc[px][j + k] += xa[px] * wa[k];
            }
        }
        __syncthreads();
    }

#pragma unroll
    for (int j = 0; j < OPT; ++j) {
        int o = og * OPT + j;
        float bv = bias ? bias[o] : 0.f;
        float tmp[4];
#pragma unroll
        for (int px = 0; px < 4; ++px) {
            float v = acc[px][j] + bv;
            if (flags & 1) v += 1e-8f;
            tmp[px] = v;
        }
        size_t yi = ((size_t)b * COUT + o) * (size_t)plane + (size_t)(p0 + pg * 4);
        if (res) {
            float4 rv = *(const float4*)&res[yi];
            tmp[0] += rv.x; tmp[1] += rv.y; tmp[2] += rv.z; tmp[3] += rv.w;
        }
        *(float4*)&Y[yi] = make_float4(tmp[0], tmp[1], tmp[2], tmp[3]);
    }
}

// ---------------------------------------------------------------- central-difference depthwise 3x3 (per-batch)
__global__ __launch_bounds__(256) void dwconv_kernel(const float* __restrict__ X,
                                                     const float* __restrict__ w9,
                                                     const float* __restrict__ ksum,
                                                     float* __restrict__ Y)
{
    int p = blockIdx.x * 256 + threadIdx.x;
    int c = blockIdx.y, b = blockIdx.z;
    int i = p >> 8, j = p & 255;
    const float* xp = X + ((size_t)(b * C_ + c)) * HW_;
    const float* wc = w9 + c * 9;
    float acc = 0.f;
#pragma unroll
    for (int di = -1; di <= 1; ++di) {
        int ii = i + di;
        if (ii < 0 || ii > 255) continue;
#pragma unroll
        for (int dj = -1; dj <= 1; ++dj) {
            int jj = j + dj;
            if (jj < 0 || jj > 255) continue;
            acc += wc[(di + 1) * 3 + (dj + 1)] * xp[ii * 256 + jj];
        }
    }
    Y[((size_t)(b * C_ + c)) * HW_ + p] = acc - 0.7f * ksum[c] * xp[p];
}

// ---------------------------------------------------------------- attention helpers (per-batch)
__global__ __launch_bounds__(256) void rownorm_kernel(const float* __restrict__ X, float* __restrict__ out)
{
    int row = blockIdx.x;     // C_ rows
    const float4* xp = (const float4*)(X + (size_t)row * HW_);
    float s = 0.f;
    for (int i = threadIdx.x; i < HW_ / 4; i += 256) {
        float4 v = xp[i];
        s += v.x * v.x + v.y * v.y + v.z * v.z + v.w * v.w;
    }
    __shared__ float red[256];
    red[threadIdx.x] = s; __syncthreads();
    for (int st = 128; st > 0; st >>= 1) {
        if (threadIdx.x < st) red[threadIdx.x] += red[threadIdx.x + st];
        __syncthreads();
    }
    if (threadIdx.x == 0) out[row] = fmaxf(sqrtf(red[0]), 1e-12f);
}

__global__ __launch_bounds__(256) void gram_kernel(const float* __restrict__ Q,
                                                   const float* __restrict__ K,
                                                   float* __restrict__ part)
{
    int sl = blockIdx.x, bh = blockIdx.y;     // 32 slices, 8 heads (b=0 per-batch)
    int b = bh >> 3, h = bh & 7;
    const float* qb = Q + ((size_t)(b * C_ + h * 16)) * HW_;
    const float* kb = K + ((size_t)(b * C_ + h * 16)) * HW_;
    __shared__ __align__(16) float qs[16][68];
    __shared__ __align__(16) float ks[16][68];
    int c = threadIdx.x >> 4, d = threadIdx.x & 15;
    float acc = 0.f;
    for (int n0 = sl * 2048; n0 < (sl + 1) * 2048; n0 += 64) {
        for (int e = threadIdx.x; e < 1024; e += 256) {
            int cc = e >> 6, nn = e & 63;
            qs[cc][nn] = qb[(size_t)cc * HW_ + n0 + nn];
            ks[cc][nn] = kb[(size_t)cc * HW_ + n0 + nn];
        }
        __syncthreads();
#pragma unroll
        for (int nn = 0; nn < 64; nn += 4) {
            float4 qv = *(const float4*)&qs[c][nn];
            float4 kv = *(const float4*)&ks[d][nn];
            acc += qv.x * kv.x + qv.y * kv.y + qv.z * kv.z + qv.w * kv.w;
        }
        __syncthreads();
    }
    part[((size_t)bh * 32 + sl) * 256 + threadIdx.x] = acc;
}

__global__ __launch_bounds__(256) void softmax_kernel(const float* __restrict__ part,
                                                      const float* __restrict__ nq,
                                                      const float* __restrict__ nk,
                                                      const float* __restrict__ temp,
                                                      float* __restrict__ attn)
{
    int bh = blockIdx.x;          // 8 per-batch
    int b = bh >> 3, h = bh & 7;
    int t = threadIdx.x;
    int c = t >> 4, d = t & 15;
    float g = 0.f;
    for (int sl = 0; sl < 32; ++sl) g += part[((size_t)bh * 32 + sl) * 256 + t];
    g *= temp[h] / (nq[b * C_ + h * 16 + c] * nk[b * C_ + h * 16 + d]);
    float m = g;
#pragma unroll
    for (int off = 8; off; off >>= 1) m = fmaxf(m, __shfl_xor(m, off, 16));
    float e = __expf(g - m);
    float ssum = e;
#pragma unroll
    for (int off = 8; off; off >>= 1) ssum += __shfl_xor(ssum, off, 16);
    attn[bh * 256 + t] = e / ssum;
}

__global__ __launch_bounds__(256) void av_kernel(const float* __restrict__ attn,
                                                 const float* __restrict__ V,
                                                 float* __restrict__ Y)
{
    __shared__ __align__(16) float kv[16][260];
    __shared__ __align__(16) float at[16][16];
    int tile = blockIdx.x, h = blockIdx.y, b = blockIdx.z;
    int n0 = tile * 256, t = threadIdx.x;
    const float* vb = V + ((size_t)(b * C_ + h * 16)) * HW_;
    at[t >> 4][t & 15] = attn[(size_t)(b * 8 + h) * 256 + (t & 15) * 16 + (t >> 4)];  // at[d][c]
    for (int e = t; e < 16 * 256; e += 256) {
        int d = e >> 8, nn = e & 255;
        kv[d][nn] = vb[(size_t)d * HW_ + n0 + nn];
    }
    __syncthreads();
    float acc[16];
#pragma unroll
    for (int cc = 0; cc < 16; ++cc) acc[cc] = 0.f;
#pragma unroll
    for (int d = 0; d < 16; ++d) {
        float kvv = kv[d][t];
        float4 a0 = *(const float4*)&at[d][0];
        float4 a1 = *(const float4*)&at[d][4];
        float4 a2 = *(const float4*)&at[d][8];
        float4 a3 = *(const float4*)&at[d][12];
        acc[0]  += a0.x * kvv; acc[1]  += a0.y * kvv; acc[2]  += a0.z * kvv; acc[3]  += a0.w * kvv;
        acc[4]  += a1.x * kvv; acc[5]  += a1.y * kvv; acc[6]  += a1.z * kvv; acc[7]  += a1.w * kvv;
        acc[8]  += a2.x * kvv; acc[9]  += a2.y * kvv; acc[10] += a2.z * kvv; acc[11] += a2.w * kvv;
        acc[12] += a3.x * kvv; acc[13] += a3.y * kvv; acc[14] += a3.z * kvv; acc[15] += a3.w * kvv;
    }
    float* yb = Y + ((size_t)(b * C_ + h * 16)) * HW_ + n0 + t;
#pragma unroll
    for (int cc = 0; cc < 16; ++cc) yb[(size_t)cc * HW_] = acc[cc];
}

// ---------------------------------------------------------------- 256-pt radix-2 DIT FFT (32 lanes/row, tw table)
__device__ __forceinline__ void fft_stages(float2* row, const float2* tw, int lane)
{
#pragma unroll
    for (int s = 1; s <= 8; ++s) {
        const int half = 1 << (s - 1);
#pragma unroll
        for (int r = 0; r < 4; ++r) {
            int jb = lane + r * 32;
            int j = jb & (half - 1);
            int g = jb >> (s - 1);
            int i1 = (g << s) + j;
            float2 w = tw[j << (8 - s)];
            float2 u = row[i1];
            float2 q = row[i1 + half];
            float2 v = make_float2(q.x * w.x - q.y * w.y, q.x * w.y + q.y * w.x);
            row[i1]        = make_float2(u.x + v.x, u.y + v.y);
            row[i1 + half] = make_float2(u.x - v.x, u.y - v.y);
        }
        __syncthreads();
    }
}

#define PI2_ 6.28318530717958647692f

__global__ __launch_bounds__(256) void rfft_rows8(const float* __restrict__ X, float2* __restrict__ S)
{
    __shared__ float2 sd[8][256];
    __shared__ float2 tw[128];
    int t = threadIdx.x;
    if (t < 128) { float sn, cs; __sincosf(-PI2_ * (float)t * (1.f / 256.f), &sn, &cs); tw[t] = make_float2(cs, sn); }
    size_t r0 = (size_t)blockIdx.x * 8;
    for (int e = t; e < 2048; e += 256) {
        int j = e >> 8, i = e & 255;
        sd[j][__brev((unsigned)i) >> 24] = make_float2(X[(r0 + j) * 256 + i], 0.f);
    }
    __syncthreads();
    fft_stages(sd[t >> 5], tw, t & 31);
    for (int e = t; e < 8 * 129; e += 256) {
        int j = e / 129, kk = e % 129;
        S[(r0 + j) * 129 + kk] = sd[j][kk];
    }
}

template<int SIGN>
__global__ __launch_bounds__(256) void cfft_cols8(float2* __restrict__ S)
{
    __shared__ float2 sd[8][256];
    __shared__ float2 tw[128];
    int t = threadIdx.x;
    if (t < 128) { float sn, cs; __sincosf((float)SIGN * PI2_ * (float)t * (1.f / 256.f), &sn, &cs); tw[t] = make_float2(cs, sn); }
    int k0 = blockIdx.x * 8;          // 17 groups
    int c = blockIdx.y;               // channel within batch
    float2* base = S + (size_t)c * (H__ * KF_);
    for (int e = t; e < 2048; e += 256) {
        int j = e & 7, h = e >> 3;
        int k = k0 + j;
        float2 v = (k < KF_) ? base[(size_t)h * KF_ + k] : make_float2(0.f, 0.f);
        sd[j][__brev((unsigned)h) >> 24] = v;
    }
    __syncthreads();
    fft_stages(sd[t >> 5], tw, t & 31);
    for (int e = t; e < 2048; e += 256) {
        int j = e & 7, h = e >> 3;
        int k = k0 + j;
        if (k < KF_) {
            float2 o = sd[j][h];
            if (SIGN > 0) { o.x *= (1.f / 256.f); o.y *= (1.f / 256.f); }
            base[(size_t)h * KF_ + k] = o;
        }
    }
}

__global__ __launch_bounds__(256) void irfft_rows8_abs(const float2* __restrict__ S, float* __restrict__ Y)
{
    __shared__ float2 sd[8][256];
    __shared__ float2 tw[128];
    int t = threadIdx.x;
    if (t < 128) { float sn, cs; __sincosf(PI2_ * (float)t * (1.f / 256.f), &sn, &cs); tw[t] = make_float2(cs, sn); }
    size_t r0 = (size_t)blockIdx.x * 8;
    for (int e = t; e < 2048; e += 256) {
        int j = e >> 8, i = e & 255;
        const float2* row = S + (r0 + j) * 129;
        float2 v;
        if (i < 129) v = row[i];
        else { float2 w2 = row[256 - i]; v = make_float2(w2.x, -w2.y); }
        sd[j][__brev((unsigned)i) >> 24] = v;
    }
    __syncthreads();
    fft_stages(sd[t >> 5], tw, t & 31);
    for (int e = t; e < 2048; e += 256) {
        int j = e >> 8, i = e & 255;
        Y[(r0 + j) * 256 + i] = fabsf(sd[j][i].x * (1.f / 256.f));
    }
}

__global__ __launch_bounds__(256) void combine_kernel(const float* __restrict__ amp,
                                                      const float* __restrict__ pha,
                                                      float2* __restrict__ S)
{
    size_t i = (size_t)blockIdx.x * 256 + threadIdx.x;
    float a = amp[i], p = pha[i];
    float sn, cs;
    __sincosf(p, &sn, &cs);
    S[i] = make_float2(a * cs + 2e-8f, a * sn + 1e-8f);
}

// ---------------------------------------------------------------- fused FFN: LN2 -> pin -> gelu*gate -> pout + residual
__global__ __launch_bounds__(256) void ffn_fused(
    const float* __restrict__ x, const float* __restrict__ fre,
    const float* __restrict__ pinT, const float* __restrict__ poutT,
    const float* __restrict__ mu2, const float* __restrict__ inv2,
    const float* __restrict__ ln2w, const float* __restrict__ ln2b,
    float* __restrict__ out)
{
    __shared__ __align__(16) float xs[256][16];
    __shared__ __align__(16) float hs[16][256];
    __shared__ __align__(16) float wa[8][256];
    __shared__ __align__(16) float wb[8][256];
    const int b = blockIdx.y;
    const size_t p0 = (size_t)blockIdx.x * 16;
    const int t = threadIdx.x;

    for (int e = t; e < 256 * 16; e += 256) {
        int c = e >> 4, p = e & 15;
        size_t gp = p0 + p;
        float v = (c < 128) ? x[((size_t)b * 128 + c) * HW_ + gp]
                            : fre[((size_t)b * 128 + (c - 128)) * HW_ + gp];
        size_t pix = (size_t)b * HW_ + gp;
        xs[c][p] = (v - mu2[pix]) * inv2[pix] * ln2w[c] + ln2b[c];
    }
    __syncthreads();

    const int pg = t & 3;     // 4 pixel groups of 4
    const int og = t >> 2;    // 64 output groups
    float a1[4][4], a2[4][4];
#pragma unroll
    for (int i = 0; i < 4; ++i)
#pragma unroll
        for (int j = 0; j < 4; ++j) { a1[i][j] = 0.f; a2[i][j] = 0.f; }

    for (int c0 = 0; c0 < 256; c0 += 8) {
        for (int e = t; e < 2048; e += 256) {
            int cc = e >> 8, o = e & 255;
            wa[cc][o] = pinT[(size_t)(c0 + cc) * 512 + o];
            wb[cc][o] = pinT[(size_t)(c0 + cc) * 512 + 256 + o];
        }
        __syncthreads();
#pragma unroll
        for (int cc = 0; cc < 8; ++cc) {
            float4 xv = *(const float4*)&xs[c0 + cc][pg * 4];
            float xa[4] = {xv.x, xv.y, xv.z, xv.w};
            float4 w1 = *(const float4*)&wa[cc][og * 4];
            float4 w2 = *(const float4*)&wb[cc][og * 4];
            float wA[4] = {w1.x, w1.y, w1.z, w1.w};
            float wB[4] = {w2.x, w2.y, w2.z, w2.w};
#pragma unroll
            for (int px = 0; px < 4; ++px)
#pragma unroll
                for (int k = 0; k < 4; ++k) {
                    a1[px][k] += xa[px] * wA[k];
                    a2[px][k] += xa[px] * wB[k];
                }
        }
        __syncthreads();
    }

#pragma unroll
    for (int px = 0; px < 4; ++px) {
        float4 hv;
        hv.x = geluf(a1[px][0]) * a2[px][0];
        hv.y = geluf(a1[px][1]) * a2[px][1];
        hv.z = geluf(a1[px][2]) * a2[px][2];
        hv.w = geluf(a1[px][3]) * a2[px][3];
        *(float4*)&hs[pg * 4 + px][og * 4] = hv;
    }
    __syncthreads();

    float accv[4][2];
#pragma unroll
    for (int px = 0; px < 4; ++px) { accv[px][0] = 0.f; accv[px][1] = 0.f; }
    float* pw = &wa[0][0];   // reuse as [16][128]
    for (int h0 = 0; h0 < 256; h0 += 16) {
        for (int e = t; e < 2048; e += 256) pw[e] = poutT[(size_t)h0 * 128 + e];
        __syncthreads();
#pragma unroll
        for (int cc = 0; cc < 16; ++cc) {
            float w0 = pw[cc * 128 + og * 2];
            float w1p = pw[cc * 128 + og * 2 + 1];
#pragma unroll
            for (int px = 0; px < 4; ++px) {
                float hv = hs[pg * 4 + px][h0 + cc];
                accv[px][0] += hv * w0;
                accv[px][1] += hv * w1p;
            }
        }
        __syncthreads();
    }

#pragma unroll
    for (int j = 0; j < 2; ++j) {
        int o = og * 2 + j;
        size_t yi = ((size_t)b * 128 + o) * HW_ + p0 + (size_t)pg * 4;
        float4 rv = *(const float4*)&x[yi];
        float4 ov;
        ov.x = accv[0][j] + rv.x;
        ov.y = accv[1][j] + rv.y;
        ov.z = accv[2][j] + rv.z;
        ov.w = accv[3][j] + rv.w;
        *(float4*)&out[yi] = ov;
    }
}

// ---------------------------------------------------------------- host
extern "C" void kernel_launch(void* const* d_in, const int* in_sizes, int n_in,
                              void* d_out, int out_size, void* d_ws, size_t ws_size,
                              hipStream_t stream)
{
    (void)in_sizes; (void)n_in; (void)out_size; (void)ws_size;
    const float* ms    = (const float*)d_in[0];
    const float* pan   = (const float*)d_in[1];
    const float* ln1w  = (const float*)d_in[2];
    const float* ln1b  = (const float*)d_in[3];
    const float* ln2w  = (const float*)d_in[4];
    const float* ln2b  = (const float*)d_in[5];
    const float* qkvw  = (const float*)d_in[6];
    const float* dww   = (const float*)d_in[7];
    const float* temp  = (const float*)d_in[8];
    const float* projw = (const float*)d_in[9];
    const float* pre1w = (const float*)d_in[10];
    const float* pre1b = (const float*)d_in[11];
    const float* pre2w = (const float*)d_in[12];
    const float* pre2b = (const float*)d_in[13];
    const float* amp1w = (const float*)d_in[14];
    const float* amp1b = (const float*)d_in[15];
    const float* amp2w = (const float*)d_in[16];
    const float* amp2b = (const float*)d_in[17];
    const float* pha1w = (const float*)d_in[18];
    const float* pha1b = (const float*)d_in[19];
    const float* pha2w = (const float*)d_in[20];
    const float* pha2b = (const float*)d_in[21];
    const float* postw = (const float*)d_in[22];
    const float* postb = (const float*)d_in[23];
    const float* pinw  = (const float*)d_in[24];
    const float* poutw = (const float*)d_in[25];

    // workspace layout (floats) — total ~229 MiB
    float* F   = (float*)d_ws;            // frefuse, B*C*HW = 33554432 f (128 MiB)
    float* WK0 = F + 33554432;            // 8388608 f (32 MiB) spatial scratch
    float* WK1 = WK0 + 8388608;           // 8454144 f (33.8 MiB) q / spectrum / amp+pha
    float* WK2 = WK1 + 8454144;           // 8454144 f (33.8 MiB) kv / AH+PH / Sc
    float* par = WK2 + 8454144;

    float* qkvT  = par;
    float* projT = qkvT  + 16384;
    float* pre1T = projT + 16384;
    float* pre2T = pre1T + 16384;
    float* postT = pre2T + 16384;
    float* amp1T = postT + 16384;   // [256][128]
    float* pha1T = amp1T + 32768;
    float* amp2T = pha1T + 32768;
    float* pha2T = amp2T + 16384;
    float* pinT  = pha2T + 16384;   // [256][512]
    float* poutT = pinT  + 131072;  // [256][128]
    float* ksumP = poutT + 32768;
    float* nqP   = ksumP + 128;
    float* nkP   = nqP   + 128;
    float* attnP = nkP   + 128;     // 2048
    float* partP = attnP + 2048;    // 65536
    float* muA   = partP + 65536;
    float* invA  = muA   + 65536;
    float* muB   = invA  + 65536;
    float* invB  = muB   + 65536;
    float* mu2   = invB  + 65536;   // 262144
    float* inv2  = mu2   + 262144;  // 262144

    float* xout = (float*)d_out;

    auto T = [&](const float* src, float* dst, int O, int Cc) {
        int n = O * Cc;
        transpose_kernel<<<(n + 255) / 256, 256, 0, stream>>>(src, dst, O, Cc);
    };
    T(qkvw, qkvT, 128, 128);   T(projw, projT, 128, 128);
    T(pre1w, pre1T, 128, 128); T(pre2w, pre2T, 128, 128);
    T(postw, postT, 128, 128);
    T(amp1w, amp1T, 128, 256); T(pha1w, pha1T, 128, 256);
    T(amp2w, amp2T, 128, 128); T(pha2w, pha2T, 128, 128);
    T(pinw, pinT, 512, 256);   T(poutw, poutT, 128, 256);
    ksum_kernel<<<1, 128, 0, stream>>>(dww, ksumP);

    const size_t CHW = (size_t)C_ * HW_;       // 8388608
    const size_t CPF = (size_t)C_ * PLANEF_;   // 4227072
    dim3 cg(HW_ / 64, 1);
    dim3 cgf(PLANEF_ / 64, 1);

    for (int b = 0; b < B_; ++b) {
        const float* msb  = ms  + (size_t)b * CHW;
        const float* panb = pan + (size_t)b * CHW;
        float* xb   = xout + (size_t)b * CHW;
        float* freb = F    + (size_t)b * CHW;

        // ---- attention ----
        ln_stats_kernel<<<256, 256, 0, stream>>>(msb,  nullptr, muA, invA);
        ln_stats_kernel<<<256, 256, 0, stream>>>(panb, nullptr, muB, invB);
        convk<128, 128, 64, 64, 0, 0, true><<<cg, 256, 0, stream>>>(
            msb, nullptr, 128, qkvT, nullptr, nullptr, WK0, HW_, 0, muA, invA, ln1w, ln1b);
        dwconv_kernel<<<dim3(256, 128, 1), 256, 0, stream>>>(WK0, dww, ksumP, WK1);   // q
        convk<128, 128, 64, 64, 0, 0, true><<<cg, 256, 0, stream>>>(
            panb, nullptr, 128, qkvT, nullptr, nullptr, WK0, HW_, 0, muB, invB, ln1w, ln1b);
        dwconv_kernel<<<dim3(256, 128, 1), 256, 0, stream>>>(WK0, dww, ksumP, WK2);   // kv
        rownorm_kernel<<<128, 256, 0, stream>>>(WK1, nqP);
        rownorm_kernel<<<128, 256, 0, stream>>>(WK2, nkP);
        gram_kernel<<<dim3(32, 8), 256, 0, stream>>>(WK1, WK2, partP);
        softmax_kernel<<<8, 256, 0, stream>>>(partP, nqP, nkP, temp, attnP);
        av_kernel<<<dim3(256, 8, 1), 256, 0, stream>>>(attnP, WK2, WK0);
        convk<128, 128, 64, 64, 0, 0, false><<<cg, 256, 0, stream>>>(
            WK0, nullptr, 128, projT, nullptr, msb, xb, HW_, 0, nullptr, nullptr, nullptr, nullptr);

        // ---- freprocess ----
        convk<128, 128, 64, 64, 0, 0, false><<<cg, 256, 0, stream>>>(
            msb, nullptr, 128, pre1T, pre1b, nullptr, WK0, HW_, 1, nullptr, nullptr, nullptr, nullptr);
        rfft_rows8<<<4096, 256, 0, stream>>>(WK0, (float2*)WK1);
        cfft_cols8<-1><<<dim3(17, 128), 256, 0, stream>>>((float2*)WK1);
        convk<128, 128, 64, 64, 1, 0, false><<<cgf, 256, 0, stream>>>(           // AH partial 1
            WK1, nullptr, 128, amp1T, amp1b, nullptr, WK2, PLANEF_, 0, nullptr, nullptr, nullptr, nullptr);
        convk<128, 128, 64, 64, 2, 0, false><<<cgf, 256, 0, stream>>>(           // PH partial 1
            WK1, nullptr, 128, pha1T, pha1b, nullptr, WK2 + CPF, PLANEF_, 0, nullptr, nullptr, nullptr, nullptr);
        convk<128, 128, 64, 64, 0, 0, false><<<cg, 256, 0, stream>>>(
            panb, nullptr, 128, pre2T, pre2b, nullptr, WK0, HW_, 1, nullptr, nullptr, nullptr, nullptr);
        rfft_rows8<<<4096, 256, 0, stream>>>(WK0, (float2*)WK1);
        cfft_cols8<-1><<<dim3(17, 128), 256, 0, stream>>>((float2*)WK1);
        convk<128, 128, 64, 64, 1, 0, false><<<cgf, 256, 0, stream>>>(           // AH partial 2 (accumulate)
            WK1, nullptr, 128, amp1T + 128 * 128, nullptr, WK2, WK2, PLANEF_, 0, nullptr, nullptr, nullptr, nullptr);
        convk<128, 128, 64, 64, 2, 0, false><<<cgf, 256, 0, stream>>>(           // PH partial 2 (accumulate)
            WK1, nullptr, 128, pha1T + 128 * 128, nullptr, WK2 + CPF, WK2 + CPF, PLANEF_, 0, nullptr, nullptr, nullptr, nullptr);
        convk<128, 128, 64, 64, 0, 1, false><<<cgf, 256, 0, stream>>>(           // amp = amp2(leaky(AH))
            WK2, nullptr, 128, amp2T, amp2b, nullptr, WK1, PLANEF_, 0, nullptr, nullptr, nullptr, nullptr);
        convk<128, 128, 64, 64, 0, 1, false><<<cgf, 256, 0, stream>>>(           // pha = pha2(leaky(PH))
            WK2 + CPF, nullptr, 128, pha2T, pha2b, nullptr, WK1 + CPF, PLANEF_, 0, nullptr, nullptr, nullptr, nullptr);
        combine_kernel<<<16512, 256, 0, stream>>>(WK1, WK1 + CPF, (float2*)WK2);
        cfft_cols8<1><<<dim3(17, 128), 256, 0, stream>>>((float2*)WK2);
        irfft_rows8_abs<<<4096, 256, 0, stream>>>((float2*)WK2, WK0);
        convk<128, 128, 64, 64, 0, 0, false><<<cg, 256, 0, stream>>>(
            WK0, nullptr, 128, postT, postb, nullptr, freb, HW_, 0, nullptr, nullptr, nullptr, nullptr);
    }

    // ---- FFN (full batch) ----
    ln_stats_kernel<<<1024, 256, 0, stream>>>(xout, F, mu2, inv2);
    ffn_fused<<<dim3(HW_ / 16, B_), 256, 0, stream>>>(xout, F, pinT, poutT, mu2, inv2, ln2w, ln2b, xout);
}

// Round 3
// 3503.275 us; speedup vs baseline: 1.8117x; 1.8117x over previous
//
#include <hip/hip_runtime.h>
#include <math.h>

#define B_ 4
#define C_ 128
#define HW_ 65536
#define H__ 256
#define KF_ 129
#define PLANEF_ 33024

typedef __attribute__((ext_vector_type(8))) short short8v;
typedef __attribute__((ext_vector_type(4))) float f32x4;

__device__ __forceinline__ float geluf(float x) {
    return 0.5f * x * (1.f + erff(x * 0.70710678118654752f));
}
__device__ __forceinline__ unsigned short f2bf(float f) {
    union { float f; unsigned u; } v; v.f = f;
    return (unsigned short)((v.u + 0x7FFFu + ((v.u >> 16) & 1u)) >> 16);
}

// ---------------------------------------------------------------- prep
__global__ __launch_bounds__(256) void tobf16_kernel(const float* __restrict__ src,
                                                     unsigned short* __restrict__ dst, int n)
{
    int i = blockIdx.x * 256 + threadIdx.x;
    if (i < n) dst[i] = f2bf(src[i]);
}

__global__ void ksum_kernel(const float* __restrict__ dw, float* __restrict__ ks)
{
    int c = threadIdx.x;
    if (c < C_) {
        float s = 0.f;
        for (int k = 0; k < 9; ++k) s += dw[c * 9 + k];
        ks[c] = s;
    }
}

// ---------------------------------------------------------------- per-pixel LayerNorm stats
__global__ __launch_bounds__(256) void ln_stats_kernel(const float* __restrict__ Xa,
                                                       const float* __restrict__ Xb,
                                                       float* __restrict__ mu, float* __restrict__ inv)
{
    int p = blockIdx.x * 256 + threadIdx.x;
    int b = p >> 16, pp = p & 65535;
    const float* a = Xa + (size_t)b * C_ * HW_ + pp;
    float s = 0.f, s2 = 0.f;
    for (int c = 0; c < C_; ++c) { float v = a[(size_t)c * HW_]; s += v; s2 += v * v; }
    float n = (float)C_;
    if (Xb) {
        const float* bb = Xb + (size_t)b * C_ * HW_ + pp;
        for (int c = 0; c < C_; ++c) { float v = bb[(size_t)c * HW_]; s += v; s2 += v * v; }
        n = 2.f * C_;
    }
    float m = s / n;
    float var = s2 / n - m * m;
    mu[p] = m;
    inv[p] = rsqrtf(var + 1e-5f);
}

// ---------------------------------------------------------------- MFMA conv1x1: Y[o][p] = epi(sum_c W[o][c]*pro(X[c][p]))
// 128 outputs x 128 pixels per block; 4 waves 2x2; K chunked by 128.
// OP: 0 float, 1 |float2|, 2 angle(float2). PRO==1: leaky(0.1) on staged input.
// LNF: LayerNorm on staged input. flags&1: +1e-8 after bias.
template<int CIN, int OP, int PRO, bool LNF>
__global__ __launch_bounds__(256, 2) void mconv(
    const void* __restrict__ X0v, const void* __restrict__ X1v, int csplit,
    const unsigned short* __restrict__ Wb, int wstride,
    const float* __restrict__ bias, const float* __restrict__ res,
    float* __restrict__ Y, int plane, int flags,
    const float* __restrict__ lnmu, const float* __restrict__ lninv,
    const float* __restrict__ lnw, const float* __restrict__ lnb)
{
    __shared__ unsigned short xs[128][136];   // [pixel][k], 16B-aligned rows
    const int t = threadIdx.x;
    const int p0 = blockIdx.x * 128;
    const int lane = t & 63;
    const int wr = t >> 7, wc = (t >> 6) & 1;
    const int lr = lane >> 4, lc = lane & 15;

    f32x4 acc[4][4];
#pragma unroll
    for (int mi = 0; mi < 4; ++mi)
#pragma unroll
        for (int ni = 0; ni < 4; ++ni) acc[mi][ni] = (f32x4){0.f, 0.f, 0.f, 0.f};

    for (int ch = 0; ch < CIN; ch += 128) {
#pragma unroll 4
        for (int i = 0; i < 64; ++i) {
            int e = t + i * 256;
            int c = e >> 7, px = e & 127;
            int cg = ch + c;
            bool inA = (cg < csplit);
            int cl = inA ? cg : cg - csplit;
            const void* Xv = inA ? X0v : X1v;
            float v;
            if constexpr (OP == 0) {
                v = ((const float*)Xv)[(size_t)cl * plane + p0 + px];
            } else {
                float2 z = ((const float2*)Xv)[(size_t)cl * plane + p0 + px];
                if constexpr (OP == 1) v = sqrtf(z.x * z.x + z.y * z.y);
                else v = atan2f(z.y, z.x);
            }
            if constexpr (PRO == 1) v = (v > 0.f) ? v : 0.1f * v;
            if constexpr (LNF) {
                int pp = p0 + px;
                v = (v - lnmu[pp]) * lninv[pp] * lnw[cg] + lnb[cg];
            }
            xs[px][c] = f2bf(v);
        }
        __syncthreads();
#pragma unroll
        for (int kk = 0; kk < 128; kk += 32) {
            short8v bfr[4];
#pragma unroll
            for (int ni = 0; ni < 4; ++ni)
                bfr[ni] = *(const short8v*)&xs[wc * 64 + ni * 16 + lc][kk + lr * 8];
#pragma unroll
            for (int mi = 0; mi < 4; ++mi) {
                int row = wr * 64 + mi * 16 + lc;
                short8v afr = *(const short8v*)(Wb + (size_t)row * wstride + ch + kk + lr * 8);
#pragma unroll
                for (int ni = 0; ni < 4; ++ni)
                    acc[mi][ni] = __builtin_amdgcn_mfma_f32_16x16x32_bf16(afr, bfr[ni], acc[mi][ni], 0, 0, 0);
            }
        }
        __syncthreads();
    }

#pragma unroll
    for (int mi = 0; mi < 4; ++mi) {
        int ob = wr * 64 + mi * 16 + lr * 4;
#pragma unroll
        for (int r = 0; r < 4; ++r) {
            int o = ob + r;
            float bv = bias ? bias[o] : 0.f;
            if (flags & 1) bv += 1e-8f;
#pragma unroll
            for (int ni = 0; ni < 4; ++ni) {
                int px = wc * 64 + ni * 16 + lc;
                float v = acc[mi][ni][r] + bv;
                size_t yi = (size_t)o * plane + p0 + px;
                if (res) v += res[yi];
                Y[yi] = v;
            }
        }
    }
}

// ---------------------------------------------------------------- fused MFMA FFN: LN2 -> pin -> gelu*gate -> pout + residual
__global__ __launch_bounds__(256) void ffn_mfma(
    const float* __restrict__ x, const float* __restrict__ fre,
    const unsigned short* __restrict__ pinb,   // [512][256] bf16
    const unsigned short* __restrict__ poutb,  // [128][256] bf16
    const float* __restrict__ mu2, const float* __restrict__ inv2,
    const float* __restrict__ ln2w, const float* __restrict__ ln2b,
    float* __restrict__ out)
{
    __shared__ unsigned short xs[64][264];     // [pixel][k]
    const int b = blockIdx.y;
    const size_t p0 = (size_t)blockIdx.x * 64;
    const int t = threadIdx.x;
    const int wave = t >> 6, lane = t & 63;
    const int lr = lane >> 4, lc = lane & 15;

    for (int i = 0; i < 64; ++i) {
        int e = t + i * 256;
        int c = e >> 6, px = e & 63;
        size_t gp = p0 + px;
        float v = (c < 128) ? x[((size_t)b * 128 + c) * HW_ + gp]
                            : fre[((size_t)b * 128 + (c - 128)) * HW_ + gp];
        size_t pix = (size_t)b * HW_ + gp;
        v = (v - mu2[pix]) * inv2[pix] * ln2w[c] + ln2b[c];
        xs[px][c] = f2bf(v);
    }
    __syncthreads();

    f32x4 a1[4][4], a2[4][4];
#pragma unroll
    for (int mi = 0; mi < 4; ++mi)
#pragma unroll
        for (int ni = 0; ni < 4; ++ni) { a1[mi][ni] = (f32x4){0.f,0.f,0.f,0.f}; a2[mi][ni] = (f32x4){0.f,0.f,0.f,0.f}; }

#pragma unroll
    for (int k0 = 0; k0 < 256; k0 += 32) {
        short8v bfr[4];
#pragma unroll
        for (int ni = 0; ni < 4; ++ni)
            bfr[ni] = *(const short8v*)&xs[ni * 16 + lc][k0 + lr * 8];
#pragma unroll
        for (int mi = 0; mi < 4; ++mi) {
            int h = wave * 64 + mi * 16 + lc;
            short8v af1 = *(const short8v*)(pinb + (size_t)h * 256 + k0 + lr * 8);
            short8v af2 = *(const short8v*)(pinb + (size_t)(256 + h) * 256 + k0 + lr * 8);
#pragma unroll
            for (int ni = 0; ni < 4; ++ni) {
                a1[mi][ni] = __builtin_amdgcn_mfma_f32_16x16x32_bf16(af1, bfr[ni], a1[mi][ni], 0, 0, 0);
                a2[mi][ni] = __builtin_amdgcn_mfma_f32_16x16x32_bf16(af2, bfr[ni], a2[mi][ni], 0, 0, 0);
            }
        }
    }
    __syncthreads();

#pragma unroll
    for (int mi = 0; mi < 4; ++mi)
#pragma unroll
        for (int ni = 0; ni < 4; ++ni)
#pragma unroll
            for (int r = 0; r < 4; ++r) {
                int h = wave * 64 + mi * 16 + lr * 4 + r;
                int px = ni * 16 + lc;
                xs[px][h] = f2bf(geluf(a1[mi][ni][r]) * a2[mi][ni][r]);
            }
    __syncthreads();

    f32x4 oc[2][4];
#pragma unroll
    for (int mi = 0; mi < 2; ++mi)
#pragma unroll
        for (int ni = 0; ni < 4; ++ni) oc[mi][ni] = (f32x4){0.f, 0.f, 0.f, 0.f};

#pragma unroll
    for (int k0 = 0; k0 < 256; k0 += 32) {
        short8v bfr[4];
#pragma unroll
        for (int ni = 0; ni < 4; ++ni)
            bfr[ni] = *(const short8v*)&xs[ni * 16 + lc][k0 + lr * 8];
#pragma unroll
        for (int mi = 0; mi < 2; ++mi) {
            int o = wave * 32 + mi * 16 + lc;
            short8v af = *(const short8v*)(poutb + (size_t)o * 256 + k0 + lr * 8);
#pragma unroll
            for (int ni = 0; ni < 4; ++ni)
                oc[mi][ni] = __builtin_amdgcn_mfma_f32_16x16x32_bf16(af, bfr[ni], oc[mi][ni], 0, 0, 0);
        }
    }

#pragma unroll
    for (int mi = 0; mi < 2; ++mi)
#pragma unroll
        for (int r = 0; r < 4; ++r) {
            int o = wave * 32 + mi * 16 + lr * 4 + r;
#pragma unroll
            for (int ni = 0; ni < 4; ++ni) {
                size_t yi = ((size_t)b * 128 + o) * HW_ + p0 + ni * 16 + lc;
                out[yi] = oc[mi][ni][r] + x[yi];
            }
        }
}

// ---------------------------------------------------------------- central-difference depthwise 3x3
__global__ __launch_bounds__(256) void dwconv_kernel(const float* __restrict__ X,
                                                     const float* __restrict__ w9,
                                                     const float* __restrict__ ksum,
                                                     float* __restrict__ Y)
{
    int p = blockIdx.x * 256 + threadIdx.x;
    int c = blockIdx.y, b = blockIdx.z;
    int i = p >> 8, j = p & 255;
    const float* xp = X + ((size_t)(b * C_ + c)) * HW_;
    const float* wc = w9 + c * 9;
    float acc = 0.f;
#pragma unroll
    for (int di = -1; di <= 1; ++di) {
        int ii = i + di;
        if (ii < 0 || ii > 255) continue;
#pragma unroll
        for (int dj = -1; dj <= 1; ++dj) {
            int jj = j + dj;
            if (jj < 0 || jj > 255) continue;
            acc += wc[(di + 1) * 3 + (dj + 1)] * xp[ii * 256 + jj];
        }
    }
    Y[((size_t)(b * C_ + c)) * HW_ + p] = acc - 0.7f * ksum[c] * xp[p];
}

// ---------------------------------------------------------------- attention helpers (per-batch)
__global__ __launch_bounds__(256) void rownorm_kernel(const float* __restrict__ X, float* __restrict__ out)
{
    int row = blockIdx.x;
    const float4* xp = (const float4*)(X + (size_t)row * HW_);
    float s = 0.f;
    for (int i = threadIdx.x; i < HW_ / 4; i += 256) {
        float4 v = xp[i];
        s += v.x * v.x + v.y * v.y + v.z * v.z + v.w * v.w;
    }
    __shared__ float red[256];
    red[threadIdx.x] = s; __syncthreads();
    for (int st = 128; st > 0; st >>= 1) {
        if (threadIdx.x < st) red[threadIdx.x] += red[threadIdx.x + st];
        __syncthreads();
    }
    if (threadIdx.x == 0) out[row] = fmaxf(sqrtf(red[0]), 1e-12f);
}

__global__ __launch_bounds__(256) void gram_kernel(const float* __restrict__ Q,
                                                   const float* __restrict__ K,
                                                   float* __restrict__ part)
{
    int sl = blockIdx.x, bh = blockIdx.y;
    int b = bh >> 3, h = bh & 7;
    const float* qb = Q + ((size_t)(b * C_ + h * 16)) * HW_;
    const float* kb = K + ((size_t)(b * C_ + h * 16)) * HW_;
    __shared__ __align__(16) float qs[16][68];
    __shared__ __align__(16) float ks[16][68];
    int c = threadIdx.x >> 4, d = threadIdx.x & 15;
    float acc = 0.f;
    for (int n0 = sl * 2048; n0 < (sl + 1) * 2048; n0 += 64) {
        for (int e = threadIdx.x; e < 1024; e += 256) {
            int cc = e >> 6, nn = e & 63;
            qs[cc][nn] = qb[(size_t)cc * HW_ + n0 + nn];
            ks[cc][nn] = kb[(size_t)cc * HW_ + n0 + nn];
        }
        __syncthreads();
#pragma unroll
        for (int nn = 0; nn < 64; nn += 4) {
            float4 qv = *(const float4*)&qs[c][nn];
            float4 kv = *(const float4*)&ks[d][nn];
            acc += qv.x * kv.x + qv.y * kv.y + qv.z * kv.z + qv.w * kv.w;
        }
        __syncthreads();
    }
    part[((size_t)bh * 32 + sl) * 256 + threadIdx.x] = acc;
}

__global__ __launch_bounds__(256) void softmax_kernel(const float* __restrict__ part,
                                                      const float* __restrict__ nq,
                                                      const float* __restrict__ nk,
                                                      const float* __restrict__ temp,
                                                      float* __restrict__ attn)
{
    int bh = blockIdx.x;
    int b = bh >> 3, h = bh & 7;
    int t = threadIdx.x;
    int c = t >> 4, d = t & 15;
    float g = 0.f;
    for (int sl = 0; sl < 32; ++sl) g += part[((size_t)bh * 32 + sl) * 256 + t];
    g *= temp[h] / (nq[b * C_ + h * 16 + c] * nk[b * C_ + h * 16 + d]);
    float m = g;
#pragma unroll
    for (int off = 8; off; off >>= 1) m = fmaxf(m, __shfl_xor(m, off, 16));
    float e = __expf(g - m);
    float ssum = e;
#pragma unroll
    for (int off = 8; off; off >>= 1) ssum += __shfl_xor(ssum, off, 16);
    attn[bh * 256 + t] = e / ssum;
}

__global__ __launch_bounds__(256) void av_kernel(const float* __restrict__ attn,
                                                 const float* __restrict__ V,
                                                 float* __restrict__ Y)
{
    __shared__ __align__(16) float kv[16][260];
    __shared__ __align__(16) float at[16][16];
    int tile = blockIdx.x, h = blockIdx.y, b = blockIdx.z;
    int n0 = tile * 256, t = threadIdx.x;
    const float* vb = V + ((size_t)(b * C_ + h * 16)) * HW_;
    at[t >> 4][t & 15] = attn[(size_t)(b * 8 + h) * 256 + (t & 15) * 16 + (t >> 4)];
    for (int e = t; e < 16 * 256; e += 256) {
        int d = e >> 8, nn = e & 255;
        kv[d][nn] = vb[(size_t)d * HW_ + n0 + nn];
    }
    __syncthreads();
    float acc[16];
#pragma unroll
    for (int cc = 0; cc < 16; ++cc) acc[cc] = 0.f;
#pragma unroll
    for (int d = 0; d < 16; ++d) {
        float kvv = kv[d][t];
        float4 a0 = *(const float4*)&at[d][0];
        float4 a1 = *(const float4*)&at[d][4];
        float4 a2 = *(const float4*)&at[d][8];
        float4 a3 = *(const float4*)&at[d][12];
        acc[0]  += a0.x * kvv; acc[1]  += a0.y * kvv; acc[2]  += a0.z * kvv; acc[3]  += a0.w * kvv;
        acc[4]  += a1.x * kvv; acc[5]  += a1.y * kvv; acc[6]  += a1.z * kvv; acc[7]  += a1.w * kvv;
        acc[8]  += a2.x * kvv; acc[9]  += a2.y * kvv; acc[10] += a2.z * kvv; acc[11] += a2.w * kvv;
        acc[12] += a3.x * kvv; acc[13] += a3.y * kvv; acc[14] += a3.z * kvv; acc[15] += a3.w * kvv;
    }
    float* yb = Y + ((size_t)(b * C_ + h * 16)) * HW_ + n0 + t;
#pragma unroll
    for (int cc = 0; cc < 16; ++cc) yb[(size_t)cc * HW_] = acc[cc];
}

// ---------------------------------------------------------------- 256-pt radix-2 DIT FFT (32 lanes/row, tw table)
__device__ __forceinline__ void fft_stages(float2* row, const float2* tw, int lane)
{
#pragma unroll
    for (int s = 1; s <= 8; ++s) {
        const int half = 1 << (s - 1);
#pragma unroll
        for (int r = 0; r < 4; ++r) {
            int jb = lane + r * 32;
            int j = jb & (half - 1);
            int g = jb >> (s - 1);
            int i1 = (g << s) + j;
            float2 w = tw[j << (8 - s)];
            float2 u = row[i1];
            float2 q = row[i1 + half];
            float2 v = make_float2(q.x * w.x - q.y * w.y, q.x * w.y + q.y * w.x);
            row[i1]        = make_float2(u.x + v.x, u.y + v.y);
            row[i1 + half] = make_float2(u.x - v.x, u.y - v.y);
        }
        __syncthreads();
    }
}

#define PI2_ 6.28318530717958647692f

__global__ __launch_bounds__(256) void rfft_rows8(const float* __restrict__ X, float2* __restrict__ S)
{
    __shared__ float2 sd[8][256];
    __shared__ float2 tw[128];
    int t = threadIdx.x;
    if (t < 128) { float sn, cs; __sincosf(-PI2_ * (float)t * (1.f / 256.f), &sn, &cs); tw[t] = make_float2(cs, sn); }
    size_t r0 = (size_t)blockIdx.x * 8;
    for (int e = t; e < 2048; e += 256) {
        int j = e >> 8, i = e & 255;
        sd[j][__brev((unsigned)i) >> 24] = make_float2(X[(r0 + j) * 256 + i], 0.f);
    }
    __syncthreads();
    fft_stages(sd[t >> 5], tw, t & 31);
    for (int e = t; e < 8 * 129; e += 256) {
        int j = e / 129, kk = e % 129;
        S[(r0 + j) * 129 + kk] = sd[j][kk];
    }
}

template<int SIGN>
__global__ __launch_bounds__(256) void cfft_cols8(float2* __restrict__ S)
{
    __shared__ float2 sd[8][256];
    __shared__ float2 tw[128];
    int t = threadIdx.x;
    if (t < 128) { float sn, cs; __sincosf((float)SIGN * PI2_ * (float)t * (1.f / 256.f), &sn, &cs); tw[t] = make_float2(cs, sn); }
    int k0 = blockIdx.x * 8;
    int c = blockIdx.y;
    float2* base = S + (size_t)c * (H__ * KF_);
    for (int e = t; e < 2048; e += 256) {
        int j = e & 7, h = e >> 3;
        int k = k0 + j;
        float2 v = (k < KF_) ? base[(size_t)h * KF_ + k] : make_float2(0.f, 0.f);
        sd[j][__brev((unsigned)h) >> 24] = v;
    }
    __syncthreads();
    fft_stages(sd[t >> 5], tw, t & 31);
    for (int e = t; e < 2048; e += 256) {
        int j = e & 7, h = e >> 3;
        int k = k0 + j;
        if (k < KF_) {
            float2 o = sd[j][h];
            if (SIGN > 0) { o.x *= (1.f / 256.f); o.y *= (1.f / 256.f); }
            base[(size_t)h * KF_ + k] = o;
        }
    }
}

__global__ __launch_bounds__(256) void irfft_rows8_abs(const float2* __restrict__ S, float* __restrict__ Y)
{
    __shared__ float2 sd[8][256];
    __shared__ float2 tw[128];
    int t = threadIdx.x;
    if (t < 128) { float sn, cs; __sincosf(PI2_ * (float)t * (1.f / 256.f), &sn, &cs); tw[t] = make_float2(cs, sn); }
    size_t r0 = (size_t)blockIdx.x * 8;
    for (int e = t; e < 2048; e += 256) {
        int j = e >> 8, i = e & 255;
        const float2* row = S + (r0 + j) * 129;
        float2 v;
        if (i < 129) v = row[i];
        else { float2 w2 = row[256 - i]; v = make_float2(w2.x, -w2.y); }
        sd[j][__brev((unsigned)i) >> 24] = v;
    }
    __syncthreads();
    fft_stages(sd[t >> 5], tw, t & 31);
    for (int e = t; e < 2048; e += 256) {
        int j = e >> 8, i = e & 255;
        Y[(r0 + j) * 256 + i] = fabsf(sd[j][i].x * (1.f / 256.f));
    }
}

__global__ __launch_bounds__(256) void combine_kernel(const float* __restrict__ amp,
                                                      const float* __restrict__ pha,
                                                      float2* __restrict__ S)
{
    size_t i = (size_t)blockIdx.x * 256 + threadIdx.x;
    float a = amp[i], p = pha[i];
    float sn, cs;
    __sincosf(p, &sn, &cs);
    S[i] = make_float2(a * cs + 2e-8f, a * sn + 1e-8f);
}

// ---------------------------------------------------------------- host
extern "C" void kernel_launch(void* const* d_in, const int* in_sizes, int n_in,
                              void* d_out, int out_size, void* d_ws, size_t ws_size,
                              hipStream_t stream)
{
    (void)in_sizes; (void)n_in; (void)out_size; (void)ws_size;
    const float* ms    = (const float*)d_in[0];
    const float* pan   = (const float*)d_in[1];
    const float* ln1w  = (const float*)d_in[2];
    const float* ln1b  = (const float*)d_in[3];
    const float* ln2w  = (const float*)d_in[4];
    const float* ln2b  = (const float*)d_in[5];
    const float* qkvw  = (const float*)d_in[6];
    const float* dww   = (const float*)d_in[7];
    const float* temp  = (const float*)d_in[8];
    const float* projw = (const float*)d_in[9];
    const float* pre1w = (const float*)d_in[10];
    const float* pre1b = (const float*)d_in[11];
    const float* pre2w = (const float*)d_in[12];
    const float* pre2b = (const float*)d_in[13];
    const float* amp1w = (const float*)d_in[14];
    const float* amp1b = (const float*)d_in[15];
    const float* amp2w = (const float*)d_in[16];
    const float* amp2b = (const float*)d_in[17];
    const float* pha1w = (const float*)d_in[18];
    const float* pha1b = (const float*)d_in[19];
    const float* pha2w = (const float*)d_in[20];
    const float* pha2b = (const float*)d_in[21];
    const float* postw = (const float*)d_in[22];
    const float* postb = (const float*)d_in[23];
    const float* pinw  = (const float*)d_in[24];
    const float* poutw = (const float*)d_in[25];

    // workspace layout — ~229 MiB total (same budget as passing round)
    float* F   = (float*)d_ws;            // 33554432 f : frefuse
    float* WK0 = F + 33554432;            // 8388608 f
    float* WK1 = WK0 + 8388608;           // 8454144 f
    float* WK2 = WK1 + 8454144;           // 8454144 f
    unsigned short* w_qkv  = (unsigned short*)(WK2 + 8454144);
    unsigned short* w_proj = w_qkv  + 16384;
    unsigned short* w_pre1 = w_proj + 16384;
    unsigned short* w_pre2 = w_pre1 + 16384;
    unsigned short* w_post = w_pre2 + 16384;
    unsigned short* w_amp1 = w_post + 16384;   // [128][256]
    unsigned short* w_pha1 = w_amp1 + 32768;
    unsigned short* w_amp2 = w_pha1 + 32768;
    unsigned short* w_pha2 = w_amp2 + 16384;
    unsigned short* w_pin  = w_pha2 + 16384;   // [512][256]
    unsigned short* w_pout = w_pin  + 131072;  // [128][256]
    float* ksumP = (float*)(w_pout + 32768);
    float* nqP   = ksumP + 128;
    float* nkP   = nqP   + 128;
    float* attnP = nkP   + 128;     // 2048
    float* partP = attnP + 2048;    // 65536
    float* muA   = partP + 65536;
    float* invA  = muA   + 65536;
    float* muB   = invA  + 65536;
    float* invB  = muB   + 65536;
    float* mu2   = invB  + 65536;   // 262144
    float* inv2  = mu2   + 262144;  // 262144

    float* xout = (float*)d_out;

    auto CVT = [&](const float* src, unsigned short* dst, int n) {
        tobf16_kernel<<<(n + 255) / 256, 256, 0, stream>>>(src, dst, n);
    };
    CVT(qkvw, w_qkv, 16384);   CVT(projw, w_proj, 16384);
    CVT(pre1w, w_pre1, 16384); CVT(pre2w, w_pre2, 16384);
    CVT(postw, w_post, 16384);
    CVT(amp1w, w_amp1, 32768); CVT(pha1w, w_pha1, 32768);
    CVT(amp2w, w_amp2, 16384); CVT(pha2w, w_pha2, 16384);
    CVT(pinw, w_pin, 131072);  CVT(poutw, w_pout, 32768);
    ksum_kernel<<<1, 128, 0, stream>>>(dww, ksumP);

    const size_t CHW = (size_t)C_ * HW_;
    const size_t CPF = (size_t)C_ * PLANEF_;   // 4227072
    const float* NUL = nullptr;

    for (int b = 0; b < B_; ++b) {
        const float* msb  = ms  + (size_t)b * CHW;
        const float* panb = pan + (size_t)b * CHW;
        float* xb   = xout + (size_t)b * CHW;
        float* freb = F    + (size_t)b * CHW;

        // ---- attention ----
        ln_stats_kernel<<<256, 256, 0, stream>>>(msb,  nullptr, muA, invA);
        ln_stats_kernel<<<256, 256, 0, stream>>>(panb, nullptr, muB, invB);
        mconv<128, 0, 0, true><<<512, 256, 0, stream>>>(
            msb, nullptr, 128, w_qkv, 128, nullptr, nullptr, WK0, HW_, 0, muA, invA, ln1w, ln1b);
        dwconv_kernel<<<dim3(256, 128, 1), 256, 0, stream>>>(WK0, dww, ksumP, WK1);   // q
        mconv<128, 0, 0, true><<<512, 256, 0, stream>>>(
            panb, nullptr, 128, w_qkv, 128, nullptr, nullptr, WK0, HW_, 0, muB, invB, ln1w, ln1b);
        dwconv_kernel<<<dim3(256, 128, 1), 256, 0, stream>>>(WK0, dww, ksumP, WK2);   // kv
        rownorm_kernel<<<128, 256, 0, stream>>>(WK1, nqP);
        rownorm_kernel<<<128, 256, 0, stream>>>(WK2, nkP);
        gram_kernel<<<dim3(32, 8), 256, 0, stream>>>(WK1, WK2, partP);
        softmax_kernel<<<8, 256, 0, stream>>>(partP, nqP, nkP, temp, attnP);
        av_kernel<<<dim3(256, 8, 1), 256, 0, stream>>>(attnP, WK2, WK0);
        mconv<128, 0, 0, false><<<512, 256, 0, stream>>>(
            WK0, nullptr, 128, w_proj, 128, nullptr, msb, xb, HW_, 0, NUL, NUL, NUL, NUL);

        // ---- freprocess ----
        mconv<128, 0, 0, false><<<512, 256, 0, stream>>>(
            msb, nullptr, 128, w_pre1, 128, pre1b, nullptr, WK0, HW_, 1, NUL, NUL, NUL, NUL);
        rfft_rows8<<<4096, 256, 0, stream>>>(WK0, (float2*)WK1);
        cfft_cols8<-1><<<dim3(17, 128), 256, 0, stream>>>((float2*)WK1);
        mconv<128, 1, 0, false><<<258, 256, 0, stream>>>(            // AH partial 1 (|msF|)
            WK1, nullptr, 128, w_amp1, 256, amp1b, nullptr, WK2, PLANEF_, 0, NUL, NUL, NUL, NUL);
        mconv<128, 2, 0, false><<<258, 256, 0, stream>>>(            // PH partial 1 (angle msF)
            WK1, nullptr, 128, w_pha1, 256, pha1b, nullptr, WK2 + CPF, PLANEF_, 0, NUL, NUL, NUL, NUL);
        mconv<128, 0, 0, false><<<512, 256, 0, stream>>>(
            panb, nullptr, 128, w_pre2, 128, pre2b, nullptr, WK0, HW_, 1, NUL, NUL, NUL, NUL);
        rfft_rows8<<<4096, 256, 0, stream>>>(WK0, (float2*)WK1);
        cfft_cols8<-1><<<dim3(17, 128), 256, 0, stream>>>((float2*)WK1);
        mconv<128, 1, 0, false><<<258, 256, 0, stream>>>(            // AH partial 2 (|panF|, accumulate)
            WK1, nullptr, 128, w_amp1 + 128, 256, nullptr, WK2, WK2, PLANEF_, 0, NUL, NUL, NUL, NUL);
        mconv<128, 2, 0, false><<<258, 256, 0, stream>>>(            // PH partial 2 (accumulate)
            WK1, nullptr, 128, w_pha1 + 128, 256, nullptr, WK2 + CPF, WK2 + CPF, PLANEF_, 0, NUL, NUL, NUL, NUL);
        mconv<128, 0, 1, false><<<258, 256, 0, stream>>>(            // amp = amp2(leaky(AH))
            WK2, nullptr, 128, w_amp2, 128, amp2b, nullptr, WK1, PLANEF_, 0, NUL, NUL, NUL, NUL);
        mconv<128, 0, 1, false><<<258, 256, 0, stream>>>(            // pha = pha2(leaky(PH))
            WK2 + CPF, nullptr, 128, w_pha2, 128, pha2b, nullptr, WK1 + CPF, PLANEF_, 0, NUL, NUL, NUL, NUL);
        combine_kernel<<<16512, 256, 0, stream>>>(WK1, WK1 + CPF, (float2*)WK2);
        cfft_cols8<1><<<dim3(17, 128), 256, 0, stream>>>((float2*)WK2);
        irfft_rows8_abs<<<4096, 256, 0, stream>>>((float2*)WK2, WK0);
        mconv<128, 0, 0, false><<<512, 256, 0, stream>>>(
            WK0, nullptr, 128, w_post, 128, postb, nullptr, freb, HW_, 0, NUL, NUL, NUL, NUL);
    }

    // ---- FFN (full batch) ----
    ln_stats_kernel<<<1024, 256, 0, stream>>>(xout, F, mu2, inv2);
    ffn_mfma<<<dim3(HW_ / 64, B_), 256, 0, stream>>>(xout, F, w_pin, w_pout, mu2, inv2, ln2w, ln2b, xout);
}

// Round 4
// 3274.661 us; speedup vs baseline: 1.9382x; 1.0698x over previous
//
#include <hip/hip_runtime.h>
#include <math.h>

#define B_ 4
#define C_ 128
#define HW_ 65536
#define H__ 256
#define KF_ 129
#define PLANEF_ 33024

typedef __attribute__((ext_vector_type(8))) short short8v;
typedef __attribute__((ext_vector_type(4))) float f32x4;

__device__ __forceinline__ float geluf(float x) {
    return 0.5f * x * (1.f + erff(x * 0.70710678118654752f));
}
__device__ __forceinline__ unsigned short f2bf(float f) {
    union { float f; unsigned u; } v; v.f = f;
    return (unsigned short)((v.u + 0x7FFFu + ((v.u >> 16) & 1u)) >> 16);
}
__device__ __forceinline__ float bf2f(unsigned short s) {
    union { unsigned u; float f; } v; v.u = (unsigned)s << 16;
    return v.f;
}

// ---------------------------------------------------------------- prep
__global__ __launch_bounds__(256) void tobf16_kernel(const float* __restrict__ src,
                                                     unsigned short* __restrict__ dst, int n)
{
    int i = blockIdx.x * 256 + threadIdx.x;
    if (i < n) dst[i] = f2bf(src[i]);
}

// fold LayerNorm into weights: Wb = bf16(W*lnw); wsum[o]=sum(bf16W'); bsum[o]=sum(W*lnb)
__global__ __launch_bounds__(128) void foldln_kernel(const float* __restrict__ W,
                                                     const float* __restrict__ lnw,
                                                     const float* __restrict__ lnb,
                                                     unsigned short* __restrict__ Wb,
                                                     float* __restrict__ wsum, float* __restrict__ bsum,
                                                     int Cc)
{
    int o = blockIdx.x, t = threadIdx.x;
    float sw = 0.f, sb = 0.f;
    for (int c = t; c < Cc; c += 128) {
        float w = W[(size_t)o * Cc + c];
        float fw = w * lnw[c];
        unsigned short us = f2bf(fw);
        Wb[(size_t)o * Cc + c] = us;
        sw += bf2f(us);
        sb += w * lnb[c];
    }
    __shared__ float r1[128], r2[128];
    r1[t] = sw; r2[t] = sb; __syncthreads();
    for (int st = 64; st; st >>= 1) {
        if (t < st) { r1[t] += r1[t + st]; r2[t] += r2[t + st]; }
        __syncthreads();
    }
    if (!t) { wsum[o] = r1[0]; bsum[o] = r2[0]; }
}

// permuted pout for half-split FFN: dst[half][o][kp] = pout[o][(kp>>5)*64 + half*32 + (kp&31)]
__global__ __launch_bounds__(256) void poutperm_kernel(const float* __restrict__ src,
                                                       unsigned short* __restrict__ dst)
{
    int i = blockIdx.x * 256 + threadIdx.x;   // 32768
    int half = i >> 14, rem = i & 16383, o = rem >> 7, kp = rem & 127;
    int h = (kp >> 5) * 64 + half * 32 + (kp & 31);
    dst[i] = f2bf(src[o * 256 + h]);
}

__global__ void ksum_kernel(const float* __restrict__ dw, float* __restrict__ ks)
{
    int c = threadIdx.x;
    if (c < C_) {
        float s = 0.f;
        for (int k = 0; k < 9; ++k) s += dw[c * 9 + k];
        ks[c] = s;
    }
}

// ---------------------------------------------------------------- MFMA conv1x1
// Y[o][p] = epi(sum_c W[o][c]*pro(X[c][p])); 128 out x 128 px per block; 4 waves 2x2.
// OP: 0 float, 1 |float2|, 2 angle(float2). PRO==1: leaky(0.1). flags&1: +1e-8 after bias.
// LNF: raw staging + in-kernel per-pixel LN stats + folded-affine epilogue (requires CIN==128, OP==0).
template<int CIN, int OP, int PRO, bool LNF>
__global__ __launch_bounds__(256, 2) void mconv(
    const void* __restrict__ X0v, const void* __restrict__ X1v, int csplit,
    const unsigned short* __restrict__ Wb, int wstride,
    const float* __restrict__ bias, const float* __restrict__ res,
    float* __restrict__ Y, int plane, int flags,
    const float* __restrict__ wsum, const float* __restrict__ bsum)
{
    __shared__ unsigned short xs[128][136];
    __shared__ float2 lnred[LNF ? 2 : 1][LNF ? 128 : 1];
    __shared__ float2 lnmi[LNF ? 128 : 1];
    const int t = threadIdx.x;
    const int p0 = blockIdx.x * 128;
    const int lane = t & 63;
    const int wr = t >> 7, wc = (t >> 6) & 1;
    const int lr = lane >> 4, lc = lane & 15;

    f32x4 acc[4][4];
#pragma unroll
    for (int mi = 0; mi < 4; ++mi)
#pragma unroll
        for (int ni = 0; ni < 4; ++ni) acc[mi][ni] = (f32x4){0.f, 0.f, 0.f, 0.f};

    for (int ch = 0; ch < CIN; ch += 128) {
        float s = 0.f, s2 = 0.f;
#pragma unroll 4
        for (int i = 0; i < 64; ++i) {
            int e = t + i * 256;
            int c = e >> 7, px = e & 127;
            int cg = ch + c;
            bool inA = (cg < csplit);
            int cl = inA ? cg : cg - csplit;
            const void* Xv = inA ? X0v : X1v;
            float v;
            if constexpr (OP == 0) {
                v = ((const float*)Xv)[(size_t)cl * plane + p0 + px];
            } else {
                float2 z = ((const float2*)Xv)[(size_t)cl * plane + p0 + px];
                if constexpr (OP == 1) v = sqrtf(z.x * z.x + z.y * z.y);
                else v = atan2f(z.y, z.x);
            }
            if constexpr (PRO == 1) v = (v > 0.f) ? v : 0.1f * v;
            if constexpr (LNF) { s += v; s2 += v * v; }
            xs[px][c] = f2bf(v);
        }
        if constexpr (LNF) lnred[t >> 7][t & 127] = make_float2(s, s2);
        __syncthreads();
        if constexpr (LNF) {
            if (t < 128) {
                float2 a = lnred[0][t], bq = lnred[1][t];
                float ss = a.x + bq.x, qq = a.y + bq.y;
                float m = ss * (1.f / 128.f);
                float inv = rsqrtf(qq * (1.f / 128.f) - m * m + 1e-5f);
                lnmi[t] = make_float2(m, inv);
            }
        }
#pragma unroll
        for (int kk = 0; kk < 128; kk += 32) {
            short8v bfr[4];
#pragma unroll
            for (int ni = 0; ni < 4; ++ni)
                bfr[ni] = *(const short8v*)&xs[wc * 64 + ni * 16 + lc][kk + lr * 8];
#pragma unroll
            for (int mi = 0; mi < 4; ++mi) {
                int row = wr * 64 + mi * 16 + lc;
                short8v afr = *(const short8v*)(Wb + (size_t)row * wstride + ch + kk + lr * 8);
#pragma unroll
                for (int ni = 0; ni < 4; ++ni)
                    acc[mi][ni] = __builtin_amdgcn_mfma_f32_16x16x32_bf16(afr, bfr[ni], acc[mi][ni], 0, 0, 0);
            }
        }
        __syncthreads();
    }

    float2 mrow[4];
    if constexpr (LNF) {
#pragma unroll
        for (int ni = 0; ni < 4; ++ni) mrow[ni] = lnmi[wc * 64 + ni * 16 + lc];
    }

#pragma unroll
    for (int mi = 0; mi < 4; ++mi) {
        int ob = wr * 64 + mi * 16 + lr * 4;
#pragma unroll
        for (int r = 0; r < 4; ++r) {
            int o = ob + r;
            float bv = 0.f, wso = 0.f;
            if constexpr (LNF) { bv = bsum[o]; wso = wsum[o]; }
            else { if (bias) bv = bias[o]; if (flags & 1) bv += 1e-8f; }
#pragma unroll
            for (int ni = 0; ni < 4; ++ni) {
                int px = wc * 64 + ni * 16 + lc;
                float v;
                if constexpr (LNF) {
                    float m = mrow[ni].x, inv = mrow[ni].y;
                    v = acc[mi][ni][r] * inv + bv - m * inv * wso;
                } else {
                    v = acc[mi][ni][r] + bv;
                }
                size_t yi = (size_t)o * plane + p0 + px;
                if (res) v += res[yi];
                Y[yi] = v;
            }
        }
    }
}

// ---------------------------------------------------------------- fused MFMA FFN (half-split, in-kernel LN2 stats, folded LN)
__global__ __launch_bounds__(256, 2) void ffn_mfma2(
    const float* __restrict__ x, const float* __restrict__ fre,
    const unsigned short* __restrict__ pinb,    // [512][256] folded bf16
    const unsigned short* __restrict__ pout2,   // [2][128][128] permuted bf16
    const float* __restrict__ pin_ws, const float* __restrict__ pin_bb,  // [512]
    float* __restrict__ out)
{
    __shared__ unsigned short xs[64][264];
    __shared__ unsigned short hs[64][136];
    __shared__ float2 sred[4][64];
    __shared__ float2 muinv[64];
    __shared__ float2 bbws[512];
    const int b = blockIdx.y;
    const size_t p0 = (size_t)blockIdx.x * 64;
    const int t = threadIdx.x;
    const int wave = t >> 6, lane = t & 63;
    const int lr = lane >> 4, lc = lane & 15;
    const int px = t & 63, cq = t >> 6;

    for (int e = t; e < 512; e += 256) bbws[e] = make_float2(pin_bb[e], pin_ws[e]);

    float s = 0.f, s2 = 0.f;
#pragma unroll 4
    for (int i = 0; i < 64; ++i) {
        int c = cq + i * 4;
        size_t gp = p0 + px;
        float v = (c < 128) ? x[((size_t)b * 128 + c) * HW_ + gp]
                            : fre[((size_t)b * 128 + (c - 128)) * HW_ + gp];
        s += v; s2 += v * v;
        xs[px][c] = f2bf(v);
    }
    sred[cq][px] = make_float2(s, s2);
    __syncthreads();
    if (t < 64) {
        float2 a0 = sred[0][t], a1 = sred[1][t], a2 = sred[2][t], a3 = sred[3][t];
        float ss = a0.x + a1.x + a2.x + a3.x;
        float qq = a0.y + a1.y + a2.y + a3.y;
        float m = ss * (1.f / 256.f);
        float inv = rsqrtf(qq * (1.f / 256.f) - m * m + 1e-5f);
        muinv[t] = make_float2(m, inv);
    }
    __syncthreads();

    float2 mrow[4];
#pragma unroll
    for (int ni = 0; ni < 4; ++ni) mrow[ni] = muinv[ni * 16 + lc];

    f32x4 oc[2][4];
#pragma unroll
    for (int mi = 0; mi < 2; ++mi)
#pragma unroll
        for (int ni = 0; ni < 4; ++ni) oc[mi][ni] = (f32x4){0.f, 0.f, 0.f, 0.f};

#pragma unroll
    for (int half = 0; half < 2; ++half) {
        f32x4 a1[2][4], a2[2][4];
#pragma unroll
        for (int mi = 0; mi < 2; ++mi)
#pragma unroll
            for (int ni = 0; ni < 4; ++ni) { a1[mi][ni] = (f32x4){0.f,0.f,0.f,0.f}; a2[mi][ni] = (f32x4){0.f,0.f,0.f,0.f}; }

#pragma unroll
        for (int k0 = 0; k0 < 256; k0 += 32) {
            short8v bfr[4];
#pragma unroll
            for (int ni = 0; ni < 4; ++ni)
                bfr[ni] = *(const short8v*)&xs[ni * 16 + lc][k0 + lr * 8];
#pragma unroll
            for (int mi = 0; mi < 2; ++mi) {
                int hrow = wave * 64 + half * 32 + mi * 16 + lc;
                short8v af1 = *(const short8v*)(pinb + (size_t)hrow * 256 + k0 + lr * 8);
                short8v af2 = *(const short8v*)(pinb + (size_t)(hrow + 256) * 256 + k0 + lr * 8);
#pragma unroll
                for (int ni = 0; ni < 4; ++ni) {
                    a1[mi][ni] = __builtin_amdgcn_mfma_f32_16x16x32_bf16(af1, bfr[ni], a1[mi][ni], 0, 0, 0);
                    a2[mi][ni] = __builtin_amdgcn_mfma_f32_16x16x32_bf16(af2, bfr[ni], a2[mi][ni], 0, 0, 0);
                }
            }
        }
        __syncthreads();   // previous-half GEMM2 readers done before hs overwrite
#pragma unroll
        for (int mi = 0; mi < 2; ++mi)
#pragma unroll
            for (int r = 0; r < 4; ++r) {
                int ho = wave * 64 + half * 32 + mi * 16 + lr * 4 + r;
                float2 bw1 = bbws[ho], bw2 = bbws[ho + 256];
                int kp = wave * 32 + mi * 16 + lr * 4 + r;
#pragma unroll
                for (int ni = 0; ni < 4; ++ni) {
                    float m = mrow[ni].x, inv = mrow[ni].y;
                    float v1 = a1[mi][ni][r] * inv + bw1.x - m * inv * bw1.y;
                    float v2 = a2[mi][ni][r] * inv + bw2.x - m * inv * bw2.y;
                    hs[ni * 16 + lc][kp] = f2bf(geluf(v1) * v2);
                }
            }
        __syncthreads();
#pragma unroll
        for (int k0 = 0; k0 < 128; k0 += 32) {
            short8v bfr2[4];
#pragma unroll
            for (int ni = 0; ni < 4; ++ni)
                bfr2[ni] = *(const short8v*)&hs[ni * 16 + lc][k0 + lr * 8];
#pragma unroll
            for (int mi = 0; mi < 2; ++mi) {
                int orow = wave * 32 + mi * 16 + lc;
                short8v af = *(const short8v*)(pout2 + half * 16384 + orow * 128 + k0 + lr * 8);
#pragma unroll
                for (int ni = 0; ni < 4; ++ni)
                    oc[mi][ni] = __builtin_amdgcn_mfma_f32_16x16x32_bf16(af, bfr2[ni], oc[mi][ni], 0, 0, 0);
            }
        }
    }

#pragma unroll
    for (int mi = 0; mi < 2; ++mi)
#pragma unroll
        for (int r = 0; r < 4; ++r) {
            int o = wave * 32 + mi * 16 + lr * 4 + r;
#pragma unroll
            for (int ni = 0; ni < 4; ++ni) {
                size_t yi = ((size_t)b * 128 + o) * HW_ + p0 + ni * 16 + lc;
                out[yi] = oc[mi][ni][r] + x[yi];
            }
        }
}

// ---------------------------------------------------------------- central-difference depthwise 3x3
__global__ __launch_bounds__(256) void dwconv_kernel(const float* __restrict__ X,
                                                     const float* __restrict__ w9,
                                                     const float* __restrict__ ksum,
                                                     float* __restrict__ Y)
{
    int p = blockIdx.x * 256 + threadIdx.x;
    int c = blockIdx.y, b = blockIdx.z;
    int i = p >> 8, j = p & 255;
    const float* xp = X + ((size_t)(b * C_ + c)) * HW_;
    const float* wc = w9 + c * 9;
    float acc = 0.f;
#pragma unroll
    for (int di = -1; di <= 1; ++di) {
        int ii = i + di;
        if (ii < 0 || ii > 255) continue;
#pragma unroll
        for (int dj = -1; dj <= 1; ++dj) {
            int jj = j + dj;
            if (jj < 0 || jj > 255) continue;
            acc += wc[(di + 1) * 3 + (dj + 1)] * xp[ii * 256 + jj];
        }
    }
    Y[((size_t)(b * C_ + c)) * HW_ + p] = acc - 0.7f * ksum[c] * xp[p];
}

// ---------------------------------------------------------------- attention helpers (per-batch)
__global__ __launch_bounds__(256) void rownorm_kernel(const float* __restrict__ X, float* __restrict__ out)
{
    int row = blockIdx.x;
    const float4* xp = (const float4*)(X + (size_t)row * HW_);
    float s = 0.f;
    for (int i = threadIdx.x; i < HW_ / 4; i += 256) {
        float4 v = xp[i];
        s += v.x * v.x + v.y * v.y + v.z * v.z + v.w * v.w;
    }
    __shared__ float red[256];
    red[threadIdx.x] = s; __syncthreads();
    for (int st = 128; st > 0; st >>= 1) {
        if (threadIdx.x < st) red[threadIdx.x] += red[threadIdx.x + st];
        __syncthreads();
    }
    if (threadIdx.x == 0) out[row] = fmaxf(sqrtf(red[0]), 1e-12f);
}

__global__ __launch_bounds__(256) void gram_kernel(const float* __restrict__ Q,
                                                   const float* __restrict__ K,
                                                   float* __restrict__ part)
{
    int sl = blockIdx.x, bh = blockIdx.y;
    int b = bh >> 3, h = bh & 7;
    const float* qb = Q + ((size_t)(b * C_ + h * 16)) * HW_;
    const float* kb = K + ((size_t)(b * C_ + h * 16)) * HW_;
    __shared__ __align__(16) float qs[16][68];
    __shared__ __align__(16) float ks[16][68];
    int c = threadIdx.x >> 4, d = threadIdx.x & 15;
    float acc = 0.f;
    for (int n0 = sl * 2048; n0 < (sl + 1) * 2048; n0 += 64) {
        for (int e = threadIdx.x; e < 1024; e += 256) {
            int cc = e >> 6, nn = e & 63;
            qs[cc][nn] = qb[(size_t)cc * HW_ + n0 + nn];
            ks[cc][nn] = kb[(size_t)cc * HW_ + n0 + nn];
        }
        __syncthreads();
#pragma unroll
        for (int nn = 0; nn < 64; nn += 4) {
            float4 qv = *(const float4*)&qs[c][nn];
            float4 kv = *(const float4*)&ks[d][nn];
            acc += qv.x * kv.x + qv.y * kv.y + qv.z * kv.z + qv.w * kv.w;
        }
        __syncthreads();
    }
    part[((size_t)bh * 32 + sl) * 256 + threadIdx.x] = acc;
}

__global__ __launch_bounds__(256) void softmax_kernel(const float* __restrict__ part,
                                                      const float* __restrict__ nq,
                                                      const float* __restrict__ nk,
                                                      const float* __restrict__ temp,
                                                      float* __restrict__ attn)
{
    int bh = blockIdx.x;
    int b = bh >> 3, h = bh & 7;
    int t = threadIdx.x;
    int c = t >> 4, d = t & 15;
    float g = 0.f;
    for (int sl = 0; sl < 32; ++sl) g += part[((size_t)bh * 32 + sl) * 256 + t];
    g *= temp[h] / (nq[b * C_ + h * 16 + c] * nk[b * C_ + h * 16 + d]);
    float m = g;
#pragma unroll
    for (int off = 8; off; off >>= 1) m = fmaxf(m, __shfl_xor(m, off, 16));
    float e = __expf(g - m);
    float ssum = e;
#pragma unroll
    for (int off = 8; off; off >>= 1) ssum += __shfl_xor(ssum, off, 16);
    attn[bh * 256 + t] = e / ssum;
}

__global__ __launch_bounds__(256) void av_kernel(const float* __restrict__ attn,
                                                 const float* __restrict__ V,
                                                 float* __restrict__ Y)
{
    __shared__ __align__(16) float kv[16][260];
    __shared__ __align__(16) float at[16][16];
    int tile = blockIdx.x, h = blockIdx.y, b = blockIdx.z;
    int n0 = tile * 256, t = threadIdx.x;
    const float* vb = V + ((size_t)(b * C_ + h * 16)) * HW_;
    at[t >> 4][t & 15] = attn[(size_t)(b * 8 + h) * 256 + (t & 15) * 16 + (t >> 4)];
    for (int e = t; e < 16 * 256; e += 256) {
        int d = e >> 8, nn = e & 255;
        kv[d][nn] = vb[(size_t)d * HW_ + n0 + nn];
    }
    __syncthreads();
    float acc[16];
#pragma unroll
    for (int cc = 0; cc < 16; ++cc) acc[cc] = 0.f;
#pragma unroll
    for (int d = 0; d < 16; ++d) {
        float kvv = kv[d][t];
        float4 a0 = *(const float4*)&at[d][0];
        float4 a1 = *(const float4*)&at[d][4];
        float4 a2 = *(const float4*)&at[d][8];
        float4 a3 = *(const float4*)&at[d][12];
        acc[0]  += a0.x * kvv; acc[1]  += a0.y * kvv; acc[2]  += a0.z * kvv; acc[3]  += a0.w * kvv;
        acc[4]  += a1.x * kvv; acc[5]  += a1.y * kvv; acc[6]  += a1.z * kvv; acc[7]  += a1.w * kvv;
        acc[8]  += a2.x * kvv; acc[9]  += a2.y * kvv; acc[10] += a2.z * kvv; acc[11] += a2.w * kvv;
        acc[12] += a3.x * kvv; acc[13] += a3.y * kvv; acc[14] += a3.z * kvv; acc[15] += a3.w * kvv;
    }
    float* yb = Y + ((size_t)(b * C_ + h * 16)) * HW_ + n0 + t;
#pragma unroll
    for (int cc = 0; cc < 16; ++cc) yb[(size_t)cc * HW_] = acc[cc];
}

// ---------------------------------------------------------------- 256-pt radix-2 DIT FFT core (32 lanes/row)
__device__ __forceinline__ void fft_stages(float2* row, const float2* tw, int lane)
{
#pragma unroll
    for (int s = 1; s <= 8; ++s) {
        const int half = 1 << (s - 1);
#pragma unroll
        for (int r = 0; r < 4; ++r) {
            int jb = lane + r * 32;
            int j = jb & (half - 1);
            int g = jb >> (s - 1);
            int i1 = (g << s) + j;
            float2 w = tw[j << (8 - s)];
            float2 u = row[i1];
            float2 q = row[i1 + half];
            float2 v = make_float2(q.x * w.x - q.y * w.y, q.x * w.y + q.y * w.x);
            row[i1]        = make_float2(u.x + v.x, u.y + v.y);
            row[i1 + half] = make_float2(u.x - v.x, u.y - v.y);
        }
        __syncthreads();
    }
}

#define PI2_ 6.28318530717958647692f

// real rows -> transposed spectrum T[c][k][h]; 8 rows (same channel) per block
__global__ __launch_bounds__(256) void rfft_rowsT(const float* __restrict__ X, float2* __restrict__ T)
{
    __shared__ float2 sd[8][256];
    __shared__ float2 tw[128];
    int t = threadIdx.x;
    if (t < 128) { float sn, cs; __sincosf(-PI2_ * (float)t * (1.f / 256.f), &sn, &cs); tw[t] = make_float2(cs, sn); }
    size_t r0 = (size_t)blockIdx.x * 8;
    int c = (int)(r0 >> 8), h0 = (int)(r0 & 255);
    for (int e = t; e < 2048; e += 256) {
        int j = e >> 8, i = e & 255;
        sd[j][__brev((unsigned)i) >> 24] = make_float2(X[(r0 + j) * 256 + i], 0.f);
    }
    __syncthreads();
    fft_stages(sd[t >> 5], tw, t & 31);
    float2* base = T + (size_t)c * PLANEF_;
    for (int e = t; e < 8 * 129; e += 256) {
        int j = e & 7, k = e >> 3;
        base[(size_t)k * 256 + h0 + j] = sd[j][k];
    }
}

// forward complex FFT along h on transposed layout (contiguous rows); 8 k-rows per block
__global__ __launch_bounds__(256) void cfftT_fwd(float2* __restrict__ T)
{
    __shared__ float2 sd[8][256];
    __shared__ float2 tw[128];
    int t = threadIdx.x;
    if (t < 128) { float sn, cs; __sincosf(-PI2_ * (float)t * (1.f / 256.f), &sn, &cs); tw[t] = make_float2(cs, sn); }
    int k0 = blockIdx.x * 8;
    int c = blockIdx.y;
    float2* base = T + (size_t)c * PLANEF_;
    for (int e = t; e < 2048; e += 256) {
        int j = e >> 8, i = e & 255;
        int k = k0 + j;
        float2 v = (k < KF_) ? base[(size_t)k * 256 + i] : make_float2(0.f, 0.f);
        sd[j][__brev((unsigned)i) >> 24] = v;
    }
    __syncthreads();
    fft_stages(sd[t >> 5], tw, t & 31);
    for (int e = t; e < 2048; e += 256) {
        int j = e >> 8, i = e & 255;
        int k = k0 + j;
        if (k < KF_) base[(size_t)k * 256 + i] = sd[j][i];
    }
}

// combine(amp,pha) + inverse h-FFT; reads T-layout amp/pha, writes ROW-MAJOR spectrum S[c][h][k]
__global__ __launch_bounds__(256) void cifft_combine(const float* __restrict__ amp,
                                                     const float* __restrict__ pha,
                                                     float2* __restrict__ S)
{
    __shared__ float2 sd[8][256];
    __shared__ float2 tw[128];
    int t = threadIdx.x;
    if (t < 128) { float sn, cs; __sincosf(PI2_ * (float)t * (1.f / 256.f), &sn, &cs); tw[t] = make_float2(cs, sn); }
    int k0 = blockIdx.x * 8;
    int c = blockIdx.y;
    const float* ab = amp + (size_t)c * PLANEF_;
    const float* pb = pha + (size_t)c * PLANEF_;
    for (int e = t; e < 2048; e += 256) {
        int j = e >> 8, i = e & 255;
        int k = k0 + j;
        float2 v = make_float2(0.f, 0.f);
        if (k < KF_) {
            float a = ab[(size_t)k * 256 + i];
            float p = pb[(size_t)k * 256 + i];
            float sn, cs;
            __sincosf(p, &sn, &cs);
            v = make_float2(a * cs + 2e-8f, a * sn + 1e-8f);
        }
        sd[j][__brev((unsigned)i) >> 24] = v;
    }
    __syncthreads();
    fft_stages(sd[t >> 5], tw, t & 31);
    float2* base = S + (size_t)c * PLANEF_;
    for (int e = t; e < 2048; e += 256) {
        int j = e & 7, h = e >> 3;
        int k = k0 + j;
        if (k < KF_) {
            float2 o = sd[j][h];
            base[(size_t)h * KF_ + k] = make_float2(o.x * (1.f / 256.f), o.y * (1.f / 256.f));
        }
    }
}

// row-major spectrum -> 256 real (Hermitian) -> |.|
__global__ __launch_bounds__(256) void irfft_rows8_abs(const float2* __restrict__ S, float* __restrict__ Y)
{
    __shared__ float2 sd[8][256];
    __shared__ float2 tw[128];
    int t = threadIdx.x;
    if (t < 128) { float sn, cs; __sincosf(PI2_ * (float)t * (1.f / 256.f), &sn, &cs); tw[t] = make_float2(cs, sn); }
    size_t r0 = (size_t)blockIdx.x * 8;
    for (int e = t; e < 2048; e += 256) {
        int j = e >> 8, i = e & 255;
        const float2* row = S + (r0 + j) * 129;
        float2 v;
        if (i < 129) v = row[i];
        else { float2 w2 = row[256 - i]; v = make_float2(w2.x, -w2.y); }
        sd[j][__brev((unsigned)i) >> 24] = v;
    }
    __syncthreads();
    fft_stages(sd[t >> 5], tw, t & 31);
    for (int e = t; e < 2048; e += 256) {
        int j = e >> 8, i = e & 255;
        Y[(r0 + j) * 256 + i] = fabsf(sd[j][i].x * (1.f / 256.f));
    }
}

// ---------------------------------------------------------------- host
extern "C" void kernel_launch(void* const* d_in, const int* in_sizes, int n_in,
                              void* d_out, int out_size, void* d_ws, size_t ws_size,
                              hipStream_t stream)
{
    (void)in_sizes; (void)n_in; (void)out_size; (void)ws_size;
    const float* ms    = (const float*)d_in[0];
    const float* pan   = (const float*)d_in[1];
    const float* ln1w  = (const float*)d_in[2];
    const float* ln1b  = (const float*)d_in[3];
    const float* ln2w  = (const float*)d_in[4];
    const float* ln2b  = (const float*)d_in[5];
    const float* qkvw  = (const float*)d_in[6];
    const float* dww   = (const float*)d_in[7];
    const float* temp  = (const float*)d_in[8];
    const float* projw = (const float*)d_in[9];
    const float* pre1w = (const float*)d_in[10];
    const float* pre1b = (const float*)d_in[11];
    const float* pre2w = (const float*)d_in[12];
    const float* pre2b = (const float*)d_in[13];
    const float* amp1w = (const float*)d_in[14];
    const float* amp1b = (const float*)d_in[15];
    const float* amp2w = (const float*)d_in[16];
    const float* amp2b = (const float*)d_in[17];
    const float* pha1w = (const float*)d_in[18];
    const float* pha1b = (const float*)d_in[19];
    const float* pha2w = (const float*)d_in[20];
    const float* pha2b = (const float*)d_in[21];
    const float* postw = (const float*)d_in[22];
    const float* postb = (const float*)d_in[23];
    const float* pinw  = (const float*)d_in[24];
    const float* poutw = (const float*)d_in[25];

    // workspace layout (floats first, then bf16 params) — within proven ~236 MB budget
    float* F   = (float*)d_ws;            // 33554432 f : frefuse
    float* WK0 = F + 33554432;            // 8388608 f
    float* WK1 = WK0 + 8388608;           // 8454144 f
    float* WK2 = WK1 + 8454144;           // 8454144 f
    unsigned short* w_qkv   = (unsigned short*)(WK2 + 8454144);
    unsigned short* w_proj  = w_qkv  + 16384;
    unsigned short* w_pre1  = w_proj + 16384;
    unsigned short* w_pre2  = w_pre1 + 16384;
    unsigned short* w_post  = w_pre2 + 16384;
    unsigned short* w_amp1  = w_post + 16384;   // [128][256]
    unsigned short* w_pha1  = w_amp1 + 32768;
    unsigned short* w_amp2  = w_pha1 + 32768;
    unsigned short* w_pha2  = w_amp2 + 16384;
    unsigned short* w_pin   = w_pha2 + 16384;   // [512][256] folded
    unsigned short* w_pout2 = w_pin  + 131072;  // [2][128][128]
    float* ksumP  = (float*)(w_pout2 + 32768);
    float* nqP    = ksumP + 128;
    float* nkP    = nqP   + 128;
    float* attnP  = nkP   + 128;     // 2048
    float* partP  = attnP + 2048;    // 65536
    float* qkv_ws = partP + 65536;   // 128
    float* qkv_bb = qkv_ws + 128;    // 128
    float* pin_ws = qkv_bb + 128;    // 512
    float* pin_bb = pin_ws + 512;    // 512

    float* xout = (float*)d_out;

    auto CVT = [&](const float* src, unsigned short* dst, int n) {
        tobf16_kernel<<<(n + 255) / 256, 256, 0, stream>>>(src, dst, n);
    };
    foldln_kernel<<<128, 128, 0, stream>>>(qkvw, ln1w, ln1b, w_qkv, qkv_ws, qkv_bb, 128);
    foldln_kernel<<<512, 128, 0, stream>>>(pinw, ln2w, ln2b, w_pin, pin_ws, pin_bb, 256);
    CVT(projw, w_proj, 16384);
    CVT(pre1w, w_pre1, 16384); CVT(pre2w, w_pre2, 16384);
    CVT(postw, w_post, 16384);
    CVT(amp1w, w_amp1, 32768); CVT(pha1w, w_pha1, 32768);
    CVT(amp2w, w_amp2, 16384); CVT(pha2w, w_pha2, 16384);
    poutperm_kernel<<<128, 256, 0, stream>>>(poutw, w_pout2);
    ksum_kernel<<<1, 128, 0, stream>>>(dww, ksumP);

    const size_t CHW = (size_t)C_ * HW_;
    const size_t CPF = (size_t)C_ * PLANEF_;   // 4227072
    const float* NUL = nullptr;

    for (int b = 0; b < B_; ++b) {
        const float* msb  = ms  + (size_t)b * CHW;
        const float* panb = pan + (size_t)b * CHW;
        float* xb   = xout + (size_t)b * CHW;
        float* freb = F    + (size_t)b * CHW;

        // ---- attention ----
        mconv<128, 0, 0, true><<<512, 256, 0, stream>>>(
            msb, nullptr, 128, w_qkv, 128, nullptr, nullptr, WK0, HW_, 0, qkv_ws, qkv_bb);
        dwconv_kernel<<<dim3(256, 128, 1), 256, 0, stream>>>(WK0, dww, ksumP, WK1);   // q
        mconv<128, 0, 0, true><<<512, 256, 0, stream>>>(
            panb, nullptr, 128, w_qkv, 128, nullptr, nullptr, WK0, HW_, 0, qkv_ws, qkv_bb);
        dwconv_kernel<<<dim3(256, 128, 1), 256, 0, stream>>>(WK0, dww, ksumP, WK2);   // kv
        rownorm_kernel<<<128, 256, 0, stream>>>(WK1, nqP);
        rownorm_kernel<<<128, 256, 0, stream>>>(WK2, nkP);
        gram_kernel<<<dim3(32, 8), 256, 0, stream>>>(WK1, WK2, partP);
        softmax_kernel<<<8, 256, 0, stream>>>(partP, nqP, nkP, temp, attnP);
        av_kernel<<<dim3(256, 8, 1), 256, 0, stream>>>(attnP, WK2, WK0);
        mconv<128, 0, 0, false><<<512, 256, 0, stream>>>(
            WK0, nullptr, 128, w_proj, 128, nullptr, msb, xb, HW_, 0, NUL, NUL);

        // ---- freprocess (transposed spectral layout) ----
        mconv<128, 0, 0, false><<<512, 256, 0, stream>>>(
            msb, nullptr, 128, w_pre1, 128, pre1b, nullptr, WK0, HW_, 1, NUL, NUL);
        rfft_rowsT<<<4096, 256, 0, stream>>>(WK0, (float2*)WK1);
        cfftT_fwd<<<dim3(17, 128), 256, 0, stream>>>((float2*)WK1);
        mconv<128, 1, 0, false><<<258, 256, 0, stream>>>(            // AH partial 1 (|msF|)
            WK1, nullptr, 128, w_amp1, 256, amp1b, nullptr, WK2, PLANEF_, 0, NUL, NUL);
        mconv<128, 2, 0, false><<<258, 256, 0, stream>>>(            // PH partial 1 (angle msF)
            WK1, nullptr, 128, w_pha1, 256, pha1b, nullptr, WK2 + CPF, PLANEF_, 0, NUL, NUL);
        mconv<128, 0, 0, false><<<512, 256, 0, stream>>>(
            panb, nullptr, 128, w_pre2, 128, pre2b, nullptr, WK0, HW_, 1, NUL, NUL);
        rfft_rowsT<<<4096, 256, 0, stream>>>(WK0, (float2*)WK1);
        cfftT_fwd<<<dim3(17, 128), 256, 0, stream>>>((float2*)WK1);
        mconv<128, 1, 0, false><<<258, 256, 0, stream>>>(            // AH partial 2 (accumulate)
            WK1, nullptr, 128, w_amp1 + 128, 256, nullptr, WK2, WK2, PLANEF_, 0, NUL, NUL);
        mconv<128, 2, 0, false><<<258, 256, 0, stream>>>(            // PH partial 2 (accumulate)
            WK1, nullptr, 128, w_pha1 + 128, 256, nullptr, WK2 + CPF, WK2 + CPF, PLANEF_, 0, NUL, NUL);
        mconv<128, 0, 1, false><<<258, 256, 0, stream>>>(            // amp = amp2(leaky(AH))
            WK2, nullptr, 128, w_amp2, 128, amp2b, nullptr, WK1, PLANEF_, 0, NUL, NUL);
        mconv<128, 0, 1, false><<<258, 256, 0, stream>>>(            // pha = pha2(leaky(PH))
            WK2 + CPF, nullptr, 128, w_pha2, 128, pha2b, nullptr, WK1 + CPF, PLANEF_, 0, NUL, NUL);
        cifft_combine<<<dim3(17, 128), 256, 0, stream>>>(WK1, WK1 + CPF, (float2*)WK2);
        irfft_rows8_abs<<<4096, 256, 0, stream>>>((float2*)WK2, WK0);
        mconv<128, 0, 0, false><<<512, 256, 0, stream>>>(
            WK0, nullptr, 128, w_post, 128, postb, nullptr, freb, HW_, 0, NUL, NUL);
    }

    // ---- FFN (full batch, LN2 fused) ----
    ffn_mfma2<<<dim3(HW_ / 64, B_), 256, 0, stream>>>(xout, F, w_pin, w_pout2, pin_ws, pin_bb, xout);
}

// Round 5
// 2418.900 us; speedup vs baseline: 2.6239x; 1.3538x over previous
//
#include <hip/hip_runtime.h>
#include <math.h>

#define B_ 4
#define C_ 128
#define HW_ 65536
#define H__ 256
#define KF_ 129
#define PLANEF_ 33024

typedef __attribute__((ext_vector_type(8))) short short8v;
typedef __attribute__((ext_vector_type(4))) float f32x4;

__device__ __forceinline__ float geluf(float x) {
    return 0.5f * x * (1.f + erff(x * 0.70710678118654752f));
}
__device__ __forceinline__ unsigned short f2bf(float f) {
    union { float f; unsigned u; } v; v.f = f;
    return (unsigned short)((v.u + 0x7FFFu + ((v.u >> 16) & 1u)) >> 16);
}
__device__ __forceinline__ float bf2f(unsigned short s) {
    union { unsigned u; float f; } v; v.u = (unsigned)s << 16;
    return v.f;
}

// ---------------------------------------------------------------- prep
__global__ __launch_bounds__(256) void tobf16_kernel(const float* __restrict__ src,
                                                     unsigned short* __restrict__ dst, int n)
{
    int i = blockIdx.x * 256 + threadIdx.x;
    if (i < n) dst[i] = f2bf(src[i]);
}

__global__ __launch_bounds__(128) void foldln_kernel(const float* __restrict__ W,
                                                     const float* __restrict__ lnw,
                                                     const float* __restrict__ lnb,
                                                     unsigned short* __restrict__ Wb,
                                                     float* __restrict__ wsum, float* __restrict__ bsum,
                                                     int Cc)
{
    int o = blockIdx.x, t = threadIdx.x;
    float sw = 0.f, sb = 0.f;
    for (int c = t; c < Cc; c += 128) {
        float w = W[(size_t)o * Cc + c];
        float fw = w * lnw[c];
        unsigned short us = f2bf(fw);
        Wb[(size_t)o * Cc + c] = us;
        sw += bf2f(us);
        sb += w * lnb[c];
    }
    __shared__ float r1[128], r2[128];
    r1[t] = sw; r2[t] = sb; __syncthreads();
    for (int st = 64; st; st >>= 1) {
        if (t < st) { r1[t] += r1[t + st]; r2[t] += r2[t + st]; }
        __syncthreads();
    }
    if (!t) { wsum[o] = r1[0]; bsum[o] = r2[0]; }
}

__global__ __launch_bounds__(256) void poutperm_kernel(const float* __restrict__ src,
                                                       unsigned short* __restrict__ dst)
{
    int i = blockIdx.x * 256 + threadIdx.x;   // 32768
    int half = i >> 14, rem = i & 16383, o = rem >> 7, kp = rem & 127;
    int h = (kp >> 5) * 64 + half * 32 + (kp & 31);
    dst[i] = f2bf(src[o * 256 + h]);
}

__global__ void pinc_kernel(const float* __restrict__ bb, const float* __restrict__ ws,
                            float4* __restrict__ pinC)
{
    int i = threadIdx.x;
    if (i < 256) pinC[i] = make_float4(bb[i], ws[i], bb[i + 256], ws[i + 256]);
}

__global__ void ksum_kernel(const float* __restrict__ dw, float* __restrict__ ks)
{
    int c = threadIdx.x;
    if (c < C_) {
        float s = 0.f;
        for (int k = 0; k < 9; ++k) s += dw[c * 9 + k];
        ks[c] = s;
    }
}

// ---------------------------------------------------------------- MFMA conv1x1 (CIN=128)
// OP: 0 float, 1 |float2|, 2 angle(float2). PRO==1: leaky(0.1). flags&1: +1e-8 after bias.
// LNF: in-kernel per-pixel LN stats (from staged bf16) + folded-affine epilogue.
// Batched via blockIdx.z with element strides sx/sres/sy.
template<int OP, int PRO, bool LNF>
__global__ __launch_bounds__(256, 3) void mconv2(
    const void* __restrict__ Xv, size_t sx,
    const unsigned short* __restrict__ Wb, int wstride,
    const float* __restrict__ bias,
    const float* __restrict__ res, size_t sres,
    float* __restrict__ Y, size_t sy, int plane, int flags,
    const float* __restrict__ wsum, const float* __restrict__ bsum)
{
    __shared__ unsigned short xs[128][136];
    __shared__ float2 lnred[LNF ? 2 : 1][LNF ? 128 : 1];
    __shared__ float2 lnmi[LNF ? 128 : 1];
    const int t = threadIdx.x;
    const int bz = blockIdx.z;
    const int p0 = blockIdx.x * 128;
    const int lane = t & 63;
    const int wr = t >> 7, wc = (t >> 6) & 1;
    const int lr = lane >> 4, lc = lane & 15;

    if constexpr (OP == 0) {
        const float* X = (const float*)Xv + (size_t)bz * sx;
#pragma unroll
        for (int g = 0; g < 2; ++g) {
            float4 st[8];
#pragma unroll
            for (int i = 0; i < 8; ++i) {
                int e = t + (g * 8 + i) * 256;           // 4096 items: 128c x 32 px4
                int c = e >> 5, px4 = e & 31;
                st[i] = *(const float4*)(X + (size_t)c * plane + p0 + px4 * 4);
            }
#pragma unroll
            for (int i = 0; i < 8; ++i) {
                int e = t + (g * 8 + i) * 256;
                int c = e >> 5, px4 = e & 31;
                float a0 = st[i].x, a1 = st[i].y, a2 = st[i].z, a3 = st[i].w;
                if constexpr (PRO == 1) {
                    a0 = a0 > 0.f ? a0 : 0.1f * a0;
                    a1 = a1 > 0.f ? a1 : 0.1f * a1;
                    a2 = a2 > 0.f ? a2 : 0.1f * a2;
                    a3 = a3 > 0.f ? a3 : 0.1f * a3;
                }
                xs[px4 * 4 + 0][c] = f2bf(a0);
                xs[px4 * 4 + 1][c] = f2bf(a1);
                xs[px4 * 4 + 2][c] = f2bf(a2);
                xs[px4 * 4 + 3][c] = f2bf(a3);
            }
        }
    } else {
        const float2* X = (const float2*)Xv + (size_t)bz * sx;
#pragma unroll
        for (int g = 0; g < 4; ++g) {
            float4 st[8];
#pragma unroll
            for (int i = 0; i < 8; ++i) {
                int e = t + (g * 8 + i) * 256;           // 8192 items: 128c x 64 px2
                int c = e >> 6, px2 = e & 63;
                st[i] = *(const float4*)(X + (size_t)c * plane + p0 + px2 * 2);
            }
#pragma unroll
            for (int i = 0; i < 8; ++i) {
                int e = t + (g * 8 + i) * 256;
                int c = e >> 6, px2 = e & 63;
                float v0, v1;
                if constexpr (OP == 1) {
                    v0 = sqrtf(st[i].x * st[i].x + st[i].y * st[i].y);
                    v1 = sqrtf(st[i].z * st[i].z + st[i].w * st[i].w);
                } else {
                    v0 = atan2f(st[i].y, st[i].x);
                    v1 = atan2f(st[i].w, st[i].z);
                }
                if constexpr (PRO == 1) {
                    v0 = v0 > 0.f ? v0 : 0.1f * v0;
                    v1 = v1 > 0.f ? v1 : 0.1f * v1;
                }
                xs[px2 * 2 + 0][c] = f2bf(v0);
                xs[px2 * 2 + 1][c] = f2bf(v1);
            }
        }
    }
    __syncthreads();

    if constexpr (LNF) {
        int px = t & 127, hf = t >> 7;
        float s = 0.f, s2 = 0.f;
#pragma unroll
        for (int j = 0; j < 8; ++j) {
            short8v v8 = *(const short8v*)&xs[px][hf * 64 + j * 8];
#pragma unroll
            for (int k = 0; k < 8; ++k) { float v = bf2f((unsigned short)v8[k]); s += v; s2 += v * v; }
        }
        lnred[hf][px] = make_float2(s, s2);
        __syncthreads();
        if (t < 128) {
            float2 a = lnred[0][t], bq = lnred[1][t];
            float ss = a.x + bq.x, qq = a.y + bq.y;
            float m = ss * (1.f / 128.f);
            float inv = rsqrtf(qq * (1.f / 128.f) - m * m + 1e-5f);
            lnmi[t] = make_float2(m, inv);
        }
        __syncthreads();
    }

    f32x4 acc[4][4];
#pragma unroll
    for (int mi = 0; mi < 4; ++mi)
#pragma unroll
        for (int ni = 0; ni < 4; ++ni) acc[mi][ni] = (f32x4){0.f, 0.f, 0.f, 0.f};

#pragma unroll
    for (int kk = 0; kk < 128; kk += 32) {
        short8v bfr[4];
#pragma unroll
        for (int ni = 0; ni < 4; ++ni)
            bfr[ni] = *(const short8v*)&xs[wc * 64 + ni * 16 + lc][kk + lr * 8];
#pragma unroll
        for (int mi = 0; mi < 4; ++mi) {
            int row = wr * 64 + mi * 16 + lc;
            short8v afr = *(const short8v*)(Wb + (size_t)row * wstride + kk + lr * 8);
#pragma unroll
            for (int ni = 0; ni < 4; ++ni)
                acc[mi][ni] = __builtin_amdgcn_mfma_f32_16x16x32_bf16(afr, bfr[ni], acc[mi][ni], 0, 0, 0);
        }
    }

    float2 mrow[4];
    if constexpr (LNF) {
#pragma unroll
        for (int ni = 0; ni < 4; ++ni) mrow[ni] = lnmi[wc * 64 + ni * 16 + lc];
    }

#pragma unroll
    for (int mi = 0; mi < 4; ++mi) {
        int ob = wr * 64 + mi * 16 + lr * 4;
#pragma unroll
        for (int r = 0; r < 4; ++r) {
            int o = ob + r;
            float bv = 0.f, wso = 0.f;
            if constexpr (LNF) { bv = bsum[o]; wso = wsum[o]; }
            else { if (bias) bv = bias[o]; if (flags & 1) bv += 1e-8f; }
#pragma unroll
            for (int ni = 0; ni < 4; ++ni) {
                int px = wc * 64 + ni * 16 + lc;
                float v;
                if constexpr (LNF) {
                    float m = mrow[ni].x, inv = mrow[ni].y;
                    v = acc[mi][ni][r] * inv + bv - m * inv * wso;
                } else {
                    v = acc[mi][ni][r] + bv;
                }
                size_t yi = (size_t)bz * sy + (size_t)o * plane + p0 + px;
                if (res) v += res[(size_t)bz * sres + (size_t)o * plane + p0 + px];
                Y[yi] = v;
            }
        }
    }
}

// ---------------------------------------------------------------- fused MFMA FFN
__global__ __launch_bounds__(256, 3) void ffn_mfma3(
    const float* __restrict__ x, const float* __restrict__ fre,
    const unsigned short* __restrict__ pinb,    // [512][256] folded bf16
    const unsigned short* __restrict__ pout2,   // [2][128][128] permuted bf16
    const float4* __restrict__ pinC,            // [256] (bb1,ws1,bb2,ws2)
    float* __restrict__ out)
{
    __shared__ unsigned short xs[64][264];
    __shared__ unsigned short hs[64][136];
    __shared__ float2 sred[4][64];
    __shared__ float2 muinv[64];
    const int b = blockIdx.y;
    const size_t p0 = (size_t)blockIdx.x * 64;
    const int t = threadIdx.x;
    const int wave = t >> 6, lane = t & 63;
    const int lr = lane >> 4, lc = lane & 15;
    const int px = t & 63, cq = t >> 6;

#pragma unroll
    for (int g = 0; g < 2; ++g) {
        float4 st[8];
#pragma unroll
        for (int i = 0; i < 8; ++i) {
            int e = t + (g * 8 + i) * 256;               // 4096 items: 256c x 16 px4
            int c = e >> 4, px4 = e & 15;
            const float* src = (c < 128) ? x + ((size_t)b * 128 + c) * HW_ + p0 + px4 * 4
                                         : fre + ((size_t)b * 128 + (c - 128)) * HW_ + p0 + px4 * 4;
            st[i] = *(const float4*)src;
        }
#pragma unroll
        for (int i = 0; i < 8; ++i) {
            int e = t + (g * 8 + i) * 256;
            int c = e >> 4, px4 = e & 15;
            xs[px4 * 4 + 0][c] = f2bf(st[i].x);
            xs[px4 * 4 + 1][c] = f2bf(st[i].y);
            xs[px4 * 4 + 2][c] = f2bf(st[i].z);
            xs[px4 * 4 + 3][c] = f2bf(st[i].w);
        }
    }
    __syncthreads();

    {
        float s = 0.f, s2 = 0.f;
#pragma unroll
        for (int j = 0; j < 8; ++j) {
            short8v v8 = *(const short8v*)&xs[px][cq * 64 + j * 8];
#pragma unroll
            for (int k = 0; k < 8; ++k) { float v = bf2f((unsigned short)v8[k]); s += v; s2 += v * v; }
        }
        sred[cq][px] = make_float2(s, s2);
    }
    __syncthreads();
    if (t < 64) {
        float2 a0 = sred[0][t], a1 = sred[1][t], a2 = sred[2][t], a3 = sred[3][t];
        float ss = a0.x + a1.x + a2.x + a3.x;
        float qq = a0.y + a1.y + a2.y + a3.y;
        float m = ss * (1.f / 256.f);
        float inv = rsqrtf(qq * (1.f / 256.f) - m * m + 1e-5f);
        muinv[t] = make_float2(m, inv);
    }
    __syncthreads();

    float2 mrow[4];
#pragma unroll
    for (int ni = 0; ni < 4; ++ni) mrow[ni] = muinv[ni * 16 + lc];

    f32x4 oc[2][4];
#pragma unroll
    for (int mi = 0; mi < 2; ++mi)
#pragma unroll
        for (int ni = 0; ni < 4; ++ni) oc[mi][ni] = (f32x4){0.f, 0.f, 0.f, 0.f};

#pragma unroll
    for (int half = 0; half < 2; ++half) {
        f32x4 a1[2][4], a2[2][4];
#pragma unroll
        for (int mi = 0; mi < 2; ++mi)
#pragma unroll
            for (int ni = 0; ni < 4; ++ni) { a1[mi][ni] = (f32x4){0.f,0.f,0.f,0.f}; a2[mi][ni] = (f32x4){0.f,0.f,0.f,0.f}; }

#pragma unroll
        for (int k0 = 0; k0 < 256; k0 += 32) {
            short8v bfr[4];
#pragma unroll
            for (int ni = 0; ni < 4; ++ni)
                bfr[ni] = *(const short8v*)&xs[ni * 16 + lc][k0 + lr * 8];
#pragma unroll
            for (int mi = 0; mi < 2; ++mi) {
                int hrow = wave * 64 + half * 32 + mi * 16 + lc;
                short8v af1 = *(const short8v*)(pinb + (size_t)hrow * 256 + k0 + lr * 8);
                short8v af2 = *(const short8v*)(pinb + (size_t)(hrow + 256) * 256 + k0 + lr * 8);
#pragma unroll
                for (int ni = 0; ni < 4; ++ni) {
                    a1[mi][ni] = __builtin_amdgcn_mfma_f32_16x16x32_bf16(af1, bfr[ni], a1[mi][ni], 0, 0, 0);
                    a2[mi][ni] = __builtin_amdgcn_mfma_f32_16x16x32_bf16(af2, bfr[ni], a2[mi][ni], 0, 0, 0);
                }
            }
        }
        __syncthreads();   // prior-half GEMM2 readers done before hs overwrite
#pragma unroll
        for (int mi = 0; mi < 2; ++mi)
#pragma unroll
            for (int r = 0; r < 4; ++r) {
                int ho = wave * 64 + half * 32 + mi * 16 + lr * 4 + r;   // [0,256)
                float4 bwc = pinC[ho];
                int kp = wave * 32 + mi * 16 + lr * 4 + r;
#pragma unroll
                for (int ni = 0; ni < 4; ++ni) {
                    float m = mrow[ni].x, inv = mrow[ni].y;
                    float v1 = a1[mi][ni][r] * inv + bwc.x - m * inv * bwc.y;
                    float v2 = a2[mi][ni][r] * inv + bwc.z - m * inv * bwc.w;
                    hs[ni * 16 + lc][kp] = f2bf(geluf(v1) * v2);
                }
            }
        __syncthreads();
#pragma unroll
        for (int k0 = 0; k0 < 128; k0 += 32) {
            short8v bfr2[4];
#pragma unroll
            for (int ni = 0; ni < 4; ++ni)
                bfr2[ni] = *(const short8v*)&hs[ni * 16 + lc][k0 + lr * 8];
#pragma unroll
            for (int mi = 0; mi < 2; ++mi) {
                int orow = wave * 32 + mi * 16 + lc;
                short8v af = *(const short8v*)(pout2 + half * 16384 + orow * 128 + k0 + lr * 8);
#pragma unroll
                for (int ni = 0; ni < 4; ++ni)
                    oc[mi][ni] = __builtin_amdgcn_mfma_f32_16x16x32_bf16(af, bfr2[ni], oc[mi][ni], 0, 0, 0);
            }
        }
    }

#pragma unroll
    for (int mi = 0; mi < 2; ++mi)
#pragma unroll
        for (int r = 0; r < 4; ++r) {
            int o = wave * 32 + mi * 16 + lr * 4 + r;
#pragma unroll
            for (int ni = 0; ni < 4; ++ni) {
                size_t yi = ((size_t)b * 128 + o) * HW_ + p0 + ni * 16 + lc;
                out[yi] = oc[mi][ni][r] + x[yi];
            }
        }
}

// ---------------------------------------------------------------- central-difference depthwise 3x3, 4px/thread
__global__ __launch_bounds__(256) void dwconv2(const float* __restrict__ X, size_t sx,
                                               const float* __restrict__ w9,
                                               const float* __restrict__ ksum,
                                               float* __restrict__ Y, size_t sy)
{
    int bz = blockIdx.z;
    int c = blockIdx.y;
    int p4 = blockIdx.x * 256 + threadIdx.x;   // 16384 groups of 4 px
    int p0 = p4 * 4;
    int i = p0 >> 8, j0 = p0 & 255;
    const float* xp = X + (size_t)bz * sx + (size_t)c * HW_;
    const float* wc = w9 + c * 9;
    float a[4] = {0.f, 0.f, 0.f, 0.f};
#pragma unroll
    for (int di = -1; di <= 1; ++di) {
        int ii = i + di;
        if (ii < 0 || ii > 255) continue;
        const float* row = xp + ii * 256;
        float4 m4 = *(const float4*)(row + j0);
        float lft = (j0 > 0) ? row[j0 - 1] : 0.f;
        float rgt = (j0 < 252) ? row[j0 + 4] : 0.f;
        float v[6] = {lft, m4.x, m4.y, m4.z, m4.w, rgt};
        float w0 = wc[(di + 1) * 3], w1 = wc[(di + 1) * 3 + 1], w2 = wc[(di + 1) * 3 + 2];
#pragma unroll
        for (int k = 0; k < 4; ++k) a[k] += w0 * v[k] + w1 * v[k + 1] + w2 * v[k + 2];
    }
    float4 ctr = *(const float4*)(xp + i * 256 + j0);
    float km = 0.7f * ksum[c];
    float4 o;
    o.x = a[0] - km * ctr.x; o.y = a[1] - km * ctr.y;
    o.z = a[2] - km * ctr.z; o.w = a[3] - km * ctr.w;
    *(float4*)(Y + (size_t)bz * sy + (size_t)c * HW_ + p0) = o;
}

// ---------------------------------------------------------------- attention helpers (batched)
__global__ __launch_bounds__(256) void rownorm_kernel(const float* __restrict__ X, size_t sx,
                                                      float* __restrict__ out)
{
    int bz = blockIdx.y;
    int row = blockIdx.x;     // C_ rows
    const float4* xp = (const float4*)(X + (size_t)bz * sx + (size_t)row * HW_);
    float s = 0.f;
    for (int i = threadIdx.x; i < HW_ / 4; i += 256) {
        float4 v = xp[i];
        s += v.x * v.x + v.y * v.y + v.z * v.z + v.w * v.w;
    }
    __shared__ float red[256];
    red[threadIdx.x] = s; __syncthreads();
    for (int st = 128; st > 0; st >>= 1) {
        if (threadIdx.x < st) red[threadIdx.x] += red[threadIdx.x + st];
        __syncthreads();
    }
    if (threadIdx.x == 0) out[bz * C_ + row] = fmaxf(sqrtf(red[0]), 1e-12f);
}

__global__ __launch_bounds__(256) void gram_kernel(const float* __restrict__ Q, size_t sq,
                                                   const float* __restrict__ K, size_t sk,
                                                   float* __restrict__ part)
{
    int sl = blockIdx.x, h = blockIdx.y, bz = blockIdx.z;
    const float* qb = Q + (size_t)bz * sq + (size_t)(h * 16) * HW_;
    const float* kb = K + (size_t)bz * sk + (size_t)(h * 16) * HW_;
    __shared__ __align__(16) float qs[16][68];
    __shared__ __align__(16) float ks[16][68];
    int c = threadIdx.x >> 4, d = threadIdx.x & 15;
    float acc = 0.f;
    for (int n0 = sl * 2048; n0 < (sl + 1) * 2048; n0 += 64) {
        for (int e = threadIdx.x; e < 1024; e += 256) {
            int cc = e >> 6, nn = e & 63;
            qs[cc][nn] = qb[(size_t)cc * HW_ + n0 + nn];
            ks[cc][nn] = kb[(size_t)cc * HW_ + n0 + nn];
        }
        __syncthreads();
#pragma unroll
        for (int nn = 0; nn < 64; nn += 4) {
            float4 qv = *(const float4*)&qs[c][nn];
            float4 kv = *(const float4*)&ks[d][nn];
            acc += qv.x * kv.x + qv.y * kv.y + qv.z * kv.z + qv.w * kv.w;
        }
        __syncthreads();
    }
    part[((size_t)(bz * 8 + h) * 32 + sl) * 256 + threadIdx.x] = acc;
}

__global__ __launch_bounds__(256) void softmax_kernel(const float* __restrict__ part,
                                                      const float* __restrict__ nq,
                                                      const float* __restrict__ nk,
                                                      const float* __restrict__ temp,
                                                      float* __restrict__ attn)
{
    int h = blockIdx.x, bz = blockIdx.y;
    int t = threadIdx.x;
    int c = t >> 4, d = t & 15;
    float g = 0.f;
    for (int sl = 0; sl < 32; ++sl) g += part[((size_t)(bz * 8 + h) * 32 + sl) * 256 + t];
    g *= temp[h] / (nq[bz * C_ + h * 16 + c] * nk[bz * C_ + h * 16 + d]);
    float m = g;
#pragma unroll
    for (int off = 8; off; off >>= 1) m = fmaxf(m, __shfl_xor(m, off, 16));
    float e = __expf(g - m);
    float ssum = e;
#pragma unroll
    for (int off = 8; off; off >>= 1) ssum += __shfl_xor(ssum, off, 16);
    attn[(bz * 8 + h) * 256 + t] = e / ssum;
}

__global__ __launch_bounds__(256) void av_kernel(const float* __restrict__ attn,
                                                 const float* __restrict__ V, size_t sv,
                                                 float* __restrict__ Y, size_t sy)
{
    __shared__ __align__(16) float kv[16][260];
    __shared__ __align__(16) float at[16][16];
    int tile = blockIdx.x, h = blockIdx.y, bz = blockIdx.z;
    int n0 = tile * 256, t = threadIdx.x;
    const float* vb = V + (size_t)bz * sv + (size_t)(h * 16) * HW_;
    at[t >> 4][t & 15] = attn[(size_t)(bz * 8 + h) * 256 + (t & 15) * 16 + (t >> 4)];
    for (int e = t; e < 16 * 256; e += 256) {
        int d = e >> 8, nn = e & 255;
        kv[d][nn] = vb[(size_t)d * HW_ + n0 + nn];
    }
    __syncthreads();
    float acc[16];
#pragma unroll
    for (int cc = 0; cc < 16; ++cc) acc[cc] = 0.f;
#pragma unroll
    for (int d = 0; d < 16; ++d) {
        float kvv = kv[d][t];
        float4 a0 = *(const float4*)&at[d][0];
        float4 a1 = *(const float4*)&at[d][4];
        float4 a2 = *(const float4*)&at[d][8];
        float4 a3 = *(const float4*)&at[d][12];
        acc[0]  += a0.x * kvv; acc[1]  += a0.y * kvv; acc[2]  += a0.z * kvv; acc[3]  += a0.w * kvv;
        acc[4]  += a1.x * kvv; acc[5]  += a1.y * kvv; acc[6]  += a1.z * kvv; acc[7]  += a1.w * kvv;
        acc[8]  += a2.x * kvv; acc[9]  += a2.y * kvv; acc[10] += a2.z * kvv; acc[11] += a2.w * kvv;
        acc[12] += a3.x * kvv; acc[13] += a3.y * kvv; acc[14] += a3.z * kvv; acc[15] += a3.w * kvv;
    }
    float* yb = Y + (size_t)bz * sy + (size_t)(h * 16) * HW_ + n0 + t;
#pragma unroll
    for (int cc = 0; cc < 16; ++cc) yb[(size_t)cc * HW_] = acc[cc];
}

// ---------------------------------------------------------------- 256-pt radix-2 DIT FFT core (32 lanes/row)
__device__ __forceinline__ void fft_stages(float2* row, const float2* tw, int lane)
{
#pragma unroll
    for (int s = 1; s <= 8; ++s) {
        const int half = 1 << (s - 1);
#pragma unroll
        for (int r = 0; r < 4; ++r) {
            int jb = lane + r * 32;
            int j = jb & (half - 1);
            int g = jb >> (s - 1);
            int i1 = (g << s) + j;
            float2 w = tw[j << (8 - s)];
            float2 u = row[i1];
            float2 q = row[i1 + half];
            float2 v = make_float2(q.x * w.x - q.y * w.y, q.x * w.y + q.y * w.x);
            row[i1]        = make_float2(u.x + v.x, u.y + v.y);
            row[i1 + half] = make_float2(u.x - v.x, u.y - v.y);
        }
        __syncthreads();
    }
}

#define PI2_ 6.28318530717958647692f

// real rows -> transposed spectrum T[c][k][h]
__global__ __launch_bounds__(256) void rfft_rowsT(const float* __restrict__ X, size_t sx,
                                                  float2* __restrict__ T, size_t st)
{
    __shared__ float2 sd[8][256];
    __shared__ float2 tw[128];
    int t = threadIdx.x;
    int bz = blockIdx.y;
    if (t < 128) { float sn, cs; __sincosf(-PI2_ * (float)t * (1.f / 256.f), &sn, &cs); tw[t] = make_float2(cs, sn); }
    size_t r0 = (size_t)blockIdx.x * 8;
    int c = (int)(r0 >> 8), h0 = (int)(r0 & 255);
    const float* Xb = X + (size_t)bz * sx;
    for (int e = t; e < 2048; e += 256) {
        int j = e >> 8, i = e & 255;
        sd[j][__brev((unsigned)i) >> 24] = make_float2(Xb[(r0 + j) * 256 + i], 0.f);
    }
    __syncthreads();
    fft_stages(sd[t >> 5], tw, t & 31);
    float2* base = T + (size_t)bz * st + (size_t)c * PLANEF_;
    for (int e = t; e < 8 * 129; e += 256) {
        int j = e & 7, k = e >> 3;
        base[(size_t)k * 256 + h0 + j] = sd[j][k];
    }
}

// forward complex FFT along h on transposed layout
__global__ __launch_bounds__(256) void cfftT_fwd(float2* __restrict__ T, size_t st)
{
    __shared__ float2 sd[8][256];
    __shared__ float2 tw[128];
    int t = threadIdx.x;
    int bz = blockIdx.z;
    if (t < 128) { float sn, cs; __sincosf(-PI2_ * (float)t * (1.f / 256.f), &sn, &cs); tw[t] = make_float2(cs, sn); }
    int k0 = blockIdx.x * 8;
    int c = blockIdx.y;
    float2* base = T + (size_t)bz * st + (size_t)c * PLANEF_;
    for (int e = t; e < 2048; e += 256) {
        int j = e >> 8, i = e & 255;
        int k = k0 + j;
        float2 v = (k < KF_) ? base[(size_t)k * 256 + i] : make_float2(0.f, 0.f);
        sd[j][__brev((unsigned)i) >> 24] = v;
    }
    __syncthreads();
    fft_stages(sd[t >> 5], tw, t & 31);
    for (int e = t; e < 2048; e += 256) {
        int j = e >> 8, i = e & 255;
        int k = k0 + j;
        if (k < KF_) base[(size_t)k * 256 + i] = sd[j][i];
    }
}

// combine(amp,pha) + inverse h-FFT; writes row-major spectrum S[c][h][k]
__global__ __launch_bounds__(256) void cifft_combine(const float* __restrict__ amp, size_t sa,
                                                     const float* __restrict__ pha, size_t sp,
                                                     float2* __restrict__ S, size_t ss)
{
    __shared__ float2 sd[8][256];
    __shared__ float2 tw[128];
    int t = threadIdx.x;
    int bz = blockIdx.z;
    if (t < 128) { float sn, cs; __sincosf(PI2_ * (float)t * (1.f / 256.f), &sn, &cs); tw[t] = make_float2(cs, sn); }
    int k0 = blockIdx.x * 8;
    int c = blockIdx.y;
    const float* ab = amp + (size_t)bz * sa + (size_t)c * PLANEF_;
    const float* pb = pha + (size_t)bz * sp + (size_t)c * PLANEF_;
    for (int e = t; e < 2048; e += 256) {
        int j = e >> 8, i = e & 255;
        int k = k0 + j;
        float2 v = make_float2(0.f, 0.f);
        if (k < KF_) {
            float a = ab[(size_t)k * 256 + i];
            float p = pb[(size_t)k * 256 + i];
            float sn, cs;
            __sincosf(p, &sn, &cs);
            v = make_float2(a * cs + 2e-8f, a * sn + 1e-8f);
        }
        sd[j][__brev((unsigned)i) >> 24] = v;
    }
    __syncthreads();
    fft_stages(sd[t >> 5], tw, t & 31);
    float2* base = S + (size_t)bz * ss + (size_t)c * PLANEF_;
    for (int e = t; e < 2048; e += 256) {
        int j = e & 7, h = e >> 3;
        int k = k0 + j;
        if (k < KF_) {
            float2 o = sd[j][h];
            base[(size_t)h * KF_ + k] = make_float2(o.x * (1.f / 256.f), o.y * (1.f / 256.f));
        }
    }
}

// row-major spectrum -> 256 real (Hermitian) -> |.|
__global__ __launch_bounds__(256) void irfft_rows8_abs(const float2* __restrict__ S, size_t ss,
                                                       float* __restrict__ Y, size_t sy)
{
    __shared__ float2 sd[8][256];
    __shared__ float2 tw[128];
    int t = threadIdx.x;
    int bz = blockIdx.y;
    if (t < 128) { float sn, cs; __sincosf(PI2_ * (float)t * (1.f / 256.f), &sn, &cs); tw[t] = make_float2(cs, sn); }
    size_t r0 = (size_t)blockIdx.x * 8;
    const float2* Sb = S + (size_t)bz * ss;
    for (int e = t; e < 2048; e += 256) {
        int j = e >> 8, i = e & 255;
        const float2* row = Sb + (r0 + j) * 129;
        float2 v;
        if (i < 129) v = row[i];
        else { float2 w2 = row[256 - i]; v = make_float2(w2.x, -w2.y); }
        sd[j][__brev((unsigned)i) >> 24] = v;
    }
    __syncthreads();
    fft_stages(sd[t >> 5], tw, t & 31);
    float* Yb = Y + (size_t)bz * sy;
    for (int e = t; e < 2048; e += 256) {
        int j = e >> 8, i = e & 255;
        Yb[(r0 + j) * 256 + i] = fabsf(sd[j][i].x * (1.f / 256.f));
    }
}

// ---------------------------------------------------------------- host
extern "C" void kernel_launch(void* const* d_in, const int* in_sizes, int n_in,
                              void* d_out, int out_size, void* d_ws, size_t ws_size,
                              hipStream_t stream)
{
    (void)in_sizes; (void)n_in; (void)out_size;
    const float* ms    = (const float*)d_in[0];
    const float* pan   = (const float*)d_in[1];
    const float* ln1w  = (const float*)d_in[2];
    const float* ln1b  = (const float*)d_in[3];
    const float* ln2w  = (const float*)d_in[4];
    const float* ln2b  = (const float*)d_in[5];
    const float* qkvw  = (const float*)d_in[6];
    const float* dww   = (const float*)d_in[7];
    const float* temp  = (const float*)d_in[8];
    const float* projw = (const float*)d_in[9];
    const float* pre1w = (const float*)d_in[10];
    const float* pre1b = (const float*)d_in[11];
    const float* pre2w = (const float*)d_in[12];
    const float* pre2b = (const float*)d_in[13];
    const float* amp1w = (const float*)d_in[14];
    const float* amp1b = (const float*)d_in[15];
    const float* amp2w = (const float*)d_in[16];
    const float* amp2b = (const float*)d_in[17];
    const float* pha1w = (const float*)d_in[18];
    const float* pha1b = (const float*)d_in[19];
    const float* pha2w = (const float*)d_in[20];
    const float* pha2b = (const float*)d_in[21];
    const float* postw = (const float*)d_in[22];
    const float* postb = (const float*)d_in[23];
    const float* pinw  = (const float*)d_in[24];
    const float* poutw = (const float*)d_in[25];

    const size_t WKS0 = 8388608, WKS1 = 8454144, WKS2 = 8454144;
    // runtime NB selection (4/2/1-way batch fusion) based on actual ws_size
    auto needf = [&](int nb) -> size_t {
        return (33554432ull + (size_t)nb * (WKS0 + WKS1 + WKS2) + 172032ull + 273792ull + 4096ull) * 4ull;
    };
    int NB = (ws_size >= needf(4)) ? 4 : ((ws_size >= needf(2)) ? 2 : 1);

    float* F   = (float*)d_ws;                       // 33554432 f : frefuse (all batches)
    float* WK0 = F + 33554432;
    float* WK1 = WK0 + (size_t)NB * WKS0;
    float* WK2 = WK1 + (size_t)NB * WKS1;
    unsigned short* w_qkv   = (unsigned short*)(WK2 + (size_t)NB * WKS2);
    unsigned short* w_proj  = w_qkv  + 16384;
    unsigned short* w_pre1  = w_proj + 16384;
    unsigned short* w_pre2  = w_pre1 + 16384;
    unsigned short* w_post  = w_pre2 + 16384;
    unsigned short* w_amp1  = w_post + 16384;   // [128][256]
    unsigned short* w_pha1  = w_amp1 + 32768;
    unsigned short* w_amp2  = w_pha1 + 32768;
    unsigned short* w_pha2  = w_amp2 + 16384;
    unsigned short* w_pin   = w_pha2 + 16384;   // [512][256] folded
    unsigned short* w_pout2 = w_pin  + 131072;  // [2][128][128]
    float* ksumP  = (float*)(w_pout2 + 32768);
    float* nqP    = ksumP + 128;     // 512
    float* nkP    = nqP   + 512;     // 512
    float* attnP  = nkP   + 512;     // 8192
    float* partP  = attnP + 8192;    // 262144
    float* qkv_ws = partP + 262144;
    float* qkv_bb = qkv_ws + 128;
    float* pin_ws = qkv_bb + 128;    // 512
    float* pin_bb = pin_ws + 512;    // 512
    float* pinC   = pin_bb + 512;    // 1024 (float4[256])

    float* xout = (float*)d_out;

    auto CVT = [&](const float* src, unsigned short* dst, int n) {
        tobf16_kernel<<<(n + 255) / 256, 256, 0, stream>>>(src, dst, n);
    };
    foldln_kernel<<<128, 128, 0, stream>>>(qkvw, ln1w, ln1b, w_qkv, qkv_ws, qkv_bb, 128);
    foldln_kernel<<<512, 128, 0, stream>>>(pinw, ln2w, ln2b, w_pin, pin_ws, pin_bb, 256);
    CVT(projw, w_proj, 16384);
    CVT(pre1w, w_pre1, 16384); CVT(pre2w, w_pre2, 16384);
    CVT(postw, w_post, 16384);
    CVT(amp1w, w_amp1, 32768); CVT(pha1w, w_pha1, 32768);
    CVT(amp2w, w_amp2, 16384); CVT(pha2w, w_pha2, 16384);
    poutperm_kernel<<<128, 256, 0, stream>>>(poutw, w_pout2);
    pinc_kernel<<<1, 256, 0, stream>>>(pin_bb, pin_ws, (float4*)pinC);
    ksum_kernel<<<1, 128, 0, stream>>>(dww, ksumP);

    const size_t CHW = (size_t)C_ * HW_;
    const size_t CPF = (size_t)C_ * PLANEF_;   // 4227072
    const float* NUL = nullptr;

    for (int b0 = 0; b0 < B_; b0 += NB) {
        const float* msb  = ms  + (size_t)b0 * CHW;
        const float* panb = pan + (size_t)b0 * CHW;
        float* xb   = xout + (size_t)b0 * CHW;
        float* freb = F    + (size_t)b0 * CHW;
        dim3 gz(512, 1, NB);
        dim3 gzf(258, 1, NB);

        // ---- attention ----
        mconv2<0, 0, true><<<gz, 256, 0, stream>>>(
            msb, CHW, w_qkv, 128, nullptr, nullptr, 0, WK0, WKS0, HW_, 0, qkv_ws, qkv_bb);
        dwconv2<<<dim3(64, 128, NB), 256, 0, stream>>>(WK0, WKS0, dww, ksumP, WK1, WKS1);   // q
        mconv2<0, 0, true><<<gz, 256, 0, stream>>>(
            panb, CHW, w_qkv, 128, nullptr, nullptr, 0, WK0, WKS0, HW_, 0, qkv_ws, qkv_bb);
        dwconv2<<<dim3(64, 128, NB), 256, 0, stream>>>(WK0, WKS0, dww, ksumP, WK2, WKS2);   // kv
        rownorm_kernel<<<dim3(128, NB), 256, 0, stream>>>(WK1, WKS1, nqP);
        rownorm_kernel<<<dim3(128, NB), 256, 0, stream>>>(WK2, WKS2, nkP);
        gram_kernel<<<dim3(32, 8, NB), 256, 0, stream>>>(WK1, WKS1, WK2, WKS2, partP);
        softmax_kernel<<<dim3(8, NB), 256, 0, stream>>>(partP, nqP, nkP, temp, attnP);
        av_kernel<<<dim3(256, 8, NB), 256, 0, stream>>>(attnP, WK2, WKS2, WK0, WKS0);
        mconv2<0, 0, false><<<gz, 256, 0, stream>>>(
            WK0, WKS0, w_proj, 128, nullptr, msb, CHW, xb, CHW, HW_, 0, NUL, NUL);

        // ---- freprocess ----
        mconv2<0, 0, false><<<gz, 256, 0, stream>>>(
            msb, CHW, w_pre1, 128, pre1b, nullptr, 0, WK0, WKS0, HW_, 1, NUL, NUL);
        rfft_rowsT<<<dim3(4096, NB), 256, 0, stream>>>(WK0, WKS0, (float2*)WK1, WKS1 / 2);
        cfftT_fwd<<<dim3(17, 128, NB), 256, 0, stream>>>((float2*)WK1, WKS1 / 2);
        mconv2<1, 0, false><<<gzf, 256, 0, stream>>>(            // AH partial 1 (|msF|)
            WK1, WKS1 / 2, w_amp1, 256, amp1b, nullptr, 0, WK2, WKS2, PLANEF_, 0, NUL, NUL);
        mconv2<2, 0, false><<<gzf, 256, 0, stream>>>(            // PH partial 1 (angle msF)
            WK1, WKS1 / 2, w_pha1, 256, pha1b, nullptr, 0, WK2 + CPF, WKS2, PLANEF_, 0, NUL, NUL);
        mconv2<0, 0, false><<<gz, 256, 0, stream>>>(
            panb, CHW, w_pre2, 128, pre2b, nullptr, 0, WK0, WKS0, HW_, 1, NUL, NUL);
        rfft_rowsT<<<dim3(4096, NB), 256, 0, stream>>>(WK0, WKS0, (float2*)WK1, WKS1 / 2);
        cfftT_fwd<<<dim3(17, 128, NB), 256, 0, stream>>>((float2*)WK1, WKS1 / 2);
        mconv2<1, 0, false><<<gzf, 256, 0, stream>>>(            // AH partial 2 (accumulate)
            WK1, WKS1 / 2, w_amp1 + 128, 256, nullptr, WK2, WKS2, WK2, WKS2, PLANEF_, 0, NUL, NUL);
        mconv2<2, 0, false><<<gzf, 256, 0, stream>>>(            // PH partial 2 (accumulate)
            WK1, WKS1 / 2, w_pha1 + 128, 256, nullptr, WK2 + CPF, WKS2, WK2 + CPF, WKS2, PLANEF_, 0, NUL, NUL);
        mconv2<0, 1, false><<<gzf, 256, 0, stream>>>(            // amp = amp2(leaky(AH))
            WK2, WKS2, w_amp2, 128, amp2b, nullptr, 0, WK1, WKS1, PLANEF_, 0, NUL, NUL);
        mconv2<0, 1, false><<<gzf, 256, 0, stream>>>(            // pha = pha2(leaky(PH))
            WK2 + CPF, WKS2, w_pha2, 128, pha2b, nullptr, 0, WK1 + CPF, WKS1, PLANEF_, 0, NUL, NUL);
        cifft_combine<<<dim3(17, 128, NB), 256, 0, stream>>>(WK1, WKS1, WK1 + CPF, WKS1, (float2*)WK2, WKS2 / 2);
        irfft_rows8_abs<<<dim3(4096, NB), 256, 0, stream>>>((float2*)WK2, WKS2 / 2, WK0, WKS0);
        mconv2<0, 0, false><<<gz, 256, 0, stream>>>(
            WK0, WKS0, w_post, 128, postb, nullptr, 0, freb, CHW, HW_, 0, NUL, NUL);
    }

    // ---- FFN (full batch, LN2 + gelu-gate fused) ----
    ffn_mfma3<<<dim3(HW_ / 64, B_), 256, 0, stream>>>(xout, F, w_pin, w_pout2, (const float4*)pinC, xout);
}